// Round 9
// baseline (1045.105 us; speedup 1.0000x reference)
//
#include <hip/hip_runtime.h>
#include <cstdint>

#define HD 64
#define NNODES 200000
#define NS_ELEMS (NNODES * HD)          // 12,800,000

typedef short bf8 __attribute__((ext_vector_type(8)));
typedef short s2v __attribute__((ext_vector_type(2)));
typedef float f32x4 __attribute__((ext_vector_type(4)));

// ---- order-preserving float <-> uint for atomicMax ----
__device__ __forceinline__ unsigned enc_f32(float f) {
    unsigned u = __float_as_uint(f);
    return (u & 0x80000000u) ? ~u : (u | 0x80000000u);
}
__device__ __forceinline__ float dec_f32(unsigned v) {
    return (v & 0x80000000u) ? __uint_as_float(v & 0x7fffffffu)
                             : __uint_as_float(~v);
}

// RNE float -> bf16 bits, and back
__device__ __forceinline__ ushort f2bf(float f) {
    unsigned u = __float_as_uint(f);
    return (ushort)((u + 0x7fffu + ((u >> 16) & 1u)) >> 16);
}
__device__ __forceinline__ float bf2f(ushort b) {
    return __uint_as_float(((unsigned)b) << 16);
}

// ---- packed 2x bf16 atomic add (fallback path only) ----
__device__ __forceinline__ void atom_pk_add_bf16(ushort* p, ushort lo, ushort hi) {
    s2v v; v[0] = (short)lo; v[1] = (short)hi;
#if __has_builtin(__builtin_amdgcn_flat_atomic_fadd_v2bf16)
    (void)__builtin_amdgcn_flat_atomic_fadd_v2bf16((s2v*)p, v);
#elif __has_builtin(__builtin_amdgcn_global_atomic_fadd_v2bf16)
    (void)__builtin_amdgcn_global_atomic_fadd_v2bf16(
        (__attribute__((address_space(1))) s2v*)p, v);
#else
    unsigned* a = (unsigned*)p;
    unsigned old = *a, assumed;
    do {
        assumed = old;
        float f0 = bf2f((ushort)(assumed & 0xffffu)) + bf2f(lo);
        float f1 = bf2f((ushort)(assumed >> 16))     + bf2f(hi);
        unsigned nv = (unsigned)f2bf(f0) | ((unsigned)f2bf(f1) << 16);
        old = atomicCAS(a, assumed, nv);
    } while (old != assumed);
#endif
}

// ================= prep: ns fp32->bf16; weights fp32 -> bf16 frag-linear =====
struct PrepArgs {
    const float* src[8];
    ushort*      dst[8];
    int din[8], dout[8], nelem[8];
};

__global__ __launch_bounds__(256) void prep_kernel(
    const float* __restrict__ ns, ushort* __restrict__ ns16, PrepArgs pa, int total)
{
    int stride = gridDim.x * 256;
    for (int i = blockIdx.x * 256 + threadIdx.x; i < total; i += stride) {
        if (i < NS_ELEMS) { ns16[i] = f2bf(ns[i]); continue; }
        int e = i - NS_ELEMS;
        #pragma unroll
        for (int m = 0; m < 8; m++) {
            if (e < pa.nelem[m]) {
                int din = pa.din[m], dout = pa.dout[m];
                int n = e / din, k = e - n * din;
                pa.dst[m][(k >> 5) * dout * 32 + n * 32 + (k & 31)] = f2bf(pa.src[m][e]);
                e = 0x7fffffff;
            } else {
                e -= pa.nelem[m];
            }
        }
    }
}

// ================= CSR build: hist -> scan -> perm ==========================
__global__ __launch_bounds__(256) void hist_kernel(
    const int* __restrict__ i0, const int* __restrict__ i1, const int* __restrict__ i2,
    int b1e, int b2e, int total, int* __restrict__ cnt)
{
    int s = blockIdx.x * 256 + threadIdx.x;
    if (s >= total) return;
    int node = (s < b1e) ? i0[s] : (s < b2e ? i1[s - b1e] : i2[s - b2e]);
    atomicAdd(&cnt[node], 1);
}

__global__ __launch_bounds__(256) void scan1_kernel(
    const int* __restrict__ cnt, int* __restrict__ startv,
    int* __restrict__ partials, int n)
{
    __shared__ int wsum[4];
    int i = blockIdx.x * 256 + threadIdx.x;
    int v = (i < n) ? cnt[i] : 0;
    int lane = threadIdx.x & 63, wid = threadIdx.x >> 6;
    int x = v;
    #pragma unroll
    for (int off = 1; off < 64; off <<= 1) {
        int y = __shfl_up(x, off);
        if (lane >= off) x += y;
    }
    if (lane == 63) wsum[wid] = x;
    __syncthreads();
    int woff = 0;
    for (int w = 0; w < wid; w++) woff += wsum[w];
    int incl = x + woff;
    if (i < n) startv[i] = incl - v;              // block-local exclusive
    if (threadIdx.x == 255) partials[blockIdx.x] = incl;
}

__global__ __launch_bounds__(1024) void scan2_kernel(int* __restrict__ partials, int nb)
{
    __shared__ int sh[1024];
    int t = threadIdx.x;
    int orig = (t < nb) ? partials[t] : 0;
    sh[t] = orig;
    __syncthreads();
    for (int off = 1; off < 1024; off <<= 1) {
        int v = (t >= off) ? sh[t - off] : 0;
        __syncthreads();
        sh[t] += v;
        __syncthreads();
    }
    if (t < nb) partials[t] = sh[t] - orig;       // exclusive
}

__global__ __launch_bounds__(256) void scan3_kernel(
    int* __restrict__ startv, int* __restrict__ offv,
    const int* __restrict__ partials, int n, int total)
{
    int i = blockIdx.x * 256 + threadIdx.x;
    if (i < n) {
        int s = startv[i] + partials[blockIdx.x];
        startv[i] = s;
        offv[i] = s;
    }
    if (i == 0) startv[n] = total;
}

// perm[s] = destination row of slot s (linear write; atomic only on hot cursors)
__global__ __launch_bounds__(256) void fill_perm(
    const int* __restrict__ i0, const int* __restrict__ i1, const int* __restrict__ i2,
    int b1e, int b2e, int total, int* __restrict__ offv, int* __restrict__ perm)
{
    int s = blockIdx.x * 256 + threadIdx.x;
    if (s >= total) return;
    int node = (s < b1e) ? i0[s] : (s < b2e ? i1[s - b1e] : i2[s - b2e]);
    perm[s] = atomicAdd(&offv[node], 1);
}

// ========= MFMA dense layer over an MT*16-row LDS tile (update/fallback) ====
template<int DIN, int DOUT, int NT, int MT, int PDIN>
__device__ __forceinline__ void mfma_layer(
    const ushort* __restrict__ WT, const float* __restrict__ bias,
    const ushort* __restrict__ Xs, int wave, int lane, f32x4 acc[MT][NT])
{
    constexpr int KS = DIN / 32;
    const int q = lane >> 4, ln = lane & 15;
    const int n0 = wave * NT * 16;
    bf8 bf[NT][KS];
    #pragma unroll
    for (int nt = 0; nt < NT; nt++) {
        float bv = bias[n0 + nt * 16 + ln];
        #pragma unroll
        for (int mt = 0; mt < MT; mt++)
            acc[mt][nt] = f32x4{bv, bv, bv, bv};
        #pragma unroll
        for (int ks = 0; ks < KS; ks++)
            bf[nt][ks] = *(const bf8*)(WT + (size_t)ks * DOUT * 32
                                          + (n0 + nt * 16 + ln) * 32 + q * 8);
    }
    #pragma unroll
    for (int mt = 0; mt < MT; mt++) {
        bf8 af[KS];
        #pragma unroll
        for (int ks = 0; ks < KS; ks++)
            af[ks] = *(const bf8*)(Xs + (mt * 16 + ln) * PDIN + ks * 32 + q * 8);
        #pragma unroll
        for (int ks = 0; ks < KS; ks++)
            #pragma unroll
            for (int nt = 0; nt < NT; nt++)
                acc[mt][nt] = __builtin_amdgcn_mfma_f32_16x16x32_bf16(
                    af[ks], bf[nt][ks], acc[mt][nt], 0, 0, 0);
    }
}

// ====== relation kernel: ONE WAVE per 16-tuple tile, no barriers ============
// A-fragments gathered DIRECTLY global->VGPR (fragment address == gathered
// node-row bytes); per-nt streamed accumulator keeps VGPR low; tiny
// wave-private LDS (16 x PD) only for the H transpose and exp staging.
// 16 independent waves/CU hide the idx->gather latency chain via TLP.
template<int A>
__global__ __launch_bounds__(64) void rel_wave(
    const ushort* __restrict__ ns16, const int* __restrict__ idx,
    const int* __restrict__ perm,
    const ushort* __restrict__ wt1, const float* __restrict__ b1,
    const ushort* __restrict__ wt2, const float* __restrict__ b2,
    ushort* __restrict__ O2, unsigned* __restrict__ Mword, int Ttup)
{
    constexpr int D  = A * HD;
    constexpr int PD = D + 8;
    constexpr int NT = D / 16;             // one wave covers ALL output cols
    constexpr int KS = D / 32;
    __shared__ __align__(16) ushort Hs[16 * PD];

    const int lane = threadIdx.x;          // 0..63, one wave
    const int q = lane >> 4, ln = lane & 15;
    const int t0 = blockIdx.x * 16;

    // node indices for my row (tuple t0+ln)
    int tr = t0 + ln; if (tr >= Ttup) tr = Ttup - 1;
    int nd[A];
    #pragma unroll
    for (int s = 0; s < A; s++) nd[s] = idx[tr * A + s];

    // layer1 A-fragments straight from global: frag(row=ln, ks) =
    //   16B of node nd[ks/2] at byte offset ((ks&1)*32 + q*8)*2
    bf8 af[KS];
    #pragma unroll
    for (int ks = 0; ks < KS; ks++)
        af[ks] = *(const bf8*)(ns16 + (size_t)nd[ks >> 1] * HD
                                     + (ks & 1) * 32 + q * 8);

    // ---- layer1: per-nt acc, stream weights (L1/L2-hot), ReLU -> Hs
    #pragma unroll
    for (int nt = 0; nt < NT; nt++) {
        float bv = b1[nt * 16 + ln];
        f32x4 acc = f32x4{bv, bv, bv, bv};
        #pragma unroll
        for (int ks = 0; ks < KS; ks++) {
            bf8 bf = *(const bf8*)(wt1 + (size_t)ks * D * 32
                                       + (nt * 16 + ln) * 32 + q * 8);
            acc = __builtin_amdgcn_mfma_f32_16x16x32_bf16(af[ks], bf, acc, 0, 0, 0);
        }
        #pragma unroll
        for (int r = 0; r < 4; r++)
            Hs[(q * 4 + r) * PD + nt * 16 + ln] = f2bf(fmaxf(acc[r], 0.f));
    }
    __syncthreads();                       // 1-wave block: ~lgkmcnt(0) only

    // layer2 A-fragments from Hs
    bf8 af2[KS];
    #pragma unroll
    for (int ks = 0; ks < KS; ks++)
        af2[ks] = *(const bf8*)(&Hs[ln * PD + ks * 32 + q * 8]);
    __syncthreads();                       // af2 in regs; Hs now reusable

    // ---- layer2 + exp staging back into Hs, track max
    float mmax = -3.0e38f;
    #pragma unroll
    for (int nt = 0; nt < NT; nt++) {
        float bv = b2[nt * 16 + ln];
        f32x4 acc = f32x4{bv, bv, bv, bv};
        #pragma unroll
        for (int ks = 0; ks < KS; ks++) {
            bf8 bf = *(const bf8*)(wt2 + (size_t)ks * D * 32
                                       + (nt * 16 + ln) * 32 + q * 8);
            acc = __builtin_amdgcn_mfma_f32_16x16x32_bf16(af2[ks], bf, acc, 0, 0, 0);
        }
        #pragma unroll
        for (int r = 0; r < 4; r++) {
            float o = acc[r];
            if (t0 + q * 4 + r < Ttup) mmax = fmaxf(mmax, o);
            Hs[(q * 4 + r) * PD + nt * 16 + ln] = f2bf(__expf(8.f * o));
        }
    }
    __syncthreads();

    // ---- scatter: full-line rows -> O2[perm[slot]] (8 lanes x 16B per row)
    #pragma unroll
    for (int t = 0; t < 2 * A; t++) {
        int lin  = lane + t * 64;          // 0 .. 128*A-1
        int slot = lin >> 3, part = lin & 7;
        int row  = slot / A, sub = slot - row * A;
        if (t0 + row < Ttup) {
            int p = perm[(t0 + row) * A + sub];
            *(uint4*)(O2 + (size_t)p * HD + part * 8) =
                *(const uint4*)(&Hs[row * PD + sub * 64 + part * 8]);
        }
    }

    // wave max -> one fire-and-forget atomic per block
    #pragma unroll
    for (int off = 32; off; off >>= 1) mmax = fmaxf(mmax, __shfl_xor(mmax, off));
    if (lane == 0) atomicMax(Mword, enc_f32(mmax));
}

// ================= relation kernel: OLD (atomic scatter, fallback) ===========
template<int A>
__global__ __launch_bounds__(256) void rel_mfma(
    const ushort* __restrict__ ns16, const int* __restrict__ idx,
    const ushort* __restrict__ wt1, const float* __restrict__ b1,
    const ushort* __restrict__ wt2, const float* __restrict__ b2,
    ushort* __restrict__ S16, unsigned* __restrict__ Mword)
{
    constexpr int D  = A * HD;
    constexpr int PD = D + 8;
    constexpr int NT = D / 64;
    __shared__ __align__(16) ushort Xs[32 * PD];
    __shared__ __align__(16) ushort Hs[32 * PD];
    __shared__ int Is[32 * A];
    __shared__ float wred[4];

    const int tid = threadIdx.x;
    const int t0  = blockIdx.x * 32;

    if (tid < 32 * A) Is[tid] = idx[t0 * A + tid];
    for (int lin = tid; lin < 32 * A * 8; lin += 256) {
        int slot = lin >> 3, part = lin & 7;
        int node = idx[t0 * A + slot];
        int row = slot / A, sub = slot - row * A;
        *(uint4*)(Xs + row * PD + sub * 64 + part * 8) =
            *(const uint4*)(ns16 + (size_t)node * HD + part * 8);
    }
    __syncthreads();

    const int wave = tid >> 6, lane = tid & 63;
    const int q = lane >> 4, ln = lane & 15, n0 = wave * NT * 16;

    f32x4 acc[2][NT];
    mfma_layer<D, D, NT, 2, PD>(wt1, b1, Xs, wave, lane, acc);
    #pragma unroll
    for (int mt = 0; mt < 2; mt++)
        #pragma unroll
        for (int nt = 0; nt < NT; nt++)
            #pragma unroll
            for (int r = 0; r < 4; r++)
                Hs[(mt * 16 + q * 4 + r) * PD + n0 + nt * 16 + ln] =
                    f2bf(fmaxf(acc[mt][nt][r], 0.f));
    __syncthreads();
    mfma_layer<D, D, NT, 2, PD>(wt2, b2, Hs, wave, lane, acc);

    float m = -3.0e38f;
    const bool even = (ln & 1) == 0;
    #pragma unroll
    for (int mt = 0; mt < 2; mt++)
        #pragma unroll
        for (int nt = 0; nt < NT; nt++) {
            int colg = n0 + nt * 16 + ln;
            int sub  = colg >> 6;
            int featp = (colg & 63) & ~1;
            float e[4], p[4];
            #pragma unroll
            for (int r = 0; r < 4; r++) {
                float o = acc[mt][nt][r];
                m = fmaxf(m, o);
                e[r] = __expf(8.f * o);
            }
            #pragma unroll
            for (int r = 0; r < 4; r++) p[r] = __shfl_xor(e[r], 1);
            #pragma unroll
            for (int j = 0; j < 2; j++) {
                int r   = even ? j : (2 + j);
                int row = mt * 16 + q * 4 + r;
                int node = Is[row * A + sub];
                ushort lo = even ? f2bf(e[r]) : f2bf(p[r]);
                ushort hi = even ? f2bf(p[r]) : f2bf(e[r]);
                atom_pk_add_bf16(S16 + (size_t)node * HD + featp, lo, hi);
            }
        }
    #pragma unroll
    for (int off = 32; off; off >>= 1) m = fmaxf(m, __shfl_xor(m, off));
    if (lane == 0) wred[wave] = m;
    __syncthreads();
    if (tid == 0)
        atomicMax(Mword, enc_f32(fmaxf(fmaxf(wred[0], wred[1]),
                                       fmaxf(wred[2], wred[3]))));
}

// ===== update kernel: contiguous segment reduce (streaming) + MFMA ==========
__global__ __launch_bounds__(256) void update_lin(
    const float* __restrict__ ns, const ushort* __restrict__ O2,
    const int* __restrict__ startv,
    const unsigned* __restrict__ Mword,
    const ushort* __restrict__ wt1, const float* __restrict__ b1,
    const ushort* __restrict__ wt2, const float* __restrict__ b2,
    float* __restrict__ out)
{
    constexpr int D = 128, PD = D + 8;
    __shared__ __align__(16) ushort Xs[32 * PD];
    __shared__ __align__(16) ushort Hs[32 * PD];

    const int tid = threadIdx.x;
    const int r0  = blockIdx.x * 32;
    const float corr = 1e-16f * __expf(8.f * dec_f32(*Mword));

    // ns half: rows 0..31, cols 64..127
    for (int lin = tid; lin < 32 * 8; lin += 256) {
        int row = lin >> 3, p8 = (lin & 7) * 8;
        const float* src = ns + (size_t)(r0 + row) * HD + p8;
        float4 a = *(const float4*)src;
        float4 b = *(const float4*)(src + 4);
        ushort tmp[8] = { f2bf(a.x), f2bf(a.y), f2bf(a.z), f2bf(a.w),
                          f2bf(b.x), f2bf(b.y), f2bf(b.z), f2bf(b.w) };
        *(uint4*)(Xs + row * PD + 64 + p8) = *(uint4*)tmp;
    }

    // segmented reduce over CONTIGUOUS rows: thread t owns (node tid>>3, feats (tid&7)*8)
    {
        const int row = tid >> 3, f0 = (tid & 7) * 8;
        const int s0 = startv[r0 + row];
        const int s1 = startv[r0 + row + 1];
        float sum[8] = {0.f, 0.f, 0.f, 0.f, 0.f, 0.f, 0.f, 0.f};
        int k = s0;
        for (; k + 1 < s1; k += 2) {
            ushort ra[8], rb[8];
            *(uint4*)ra = *(const uint4*)(O2 + (size_t)k * HD + f0);
            *(uint4*)rb = *(const uint4*)(O2 + (size_t)(k + 1) * HD + f0);
            #pragma unroll
            for (int j = 0; j < 8; j++) sum[j] += bf2f(ra[j]) + bf2f(rb[j]);
        }
        if (k < s1) {
            ushort ra[8];
            *(uint4*)ra = *(const uint4*)(O2 + (size_t)k * HD + f0);
            #pragma unroll
            for (int j = 0; j < 8; j++) sum[j] += bf2f(ra[j]);
        }
        ushort tmp[8];
        #pragma unroll
        for (int j = 0; j < 8; j++)
            tmp[j] = f2bf(0.125f * __logf(sum[j] + corr));
        *(uint4*)(Xs + row * PD + f0) = *(uint4*)tmp;
    }
    __syncthreads();

    const int wave = tid >> 6, lane = tid & 63;
    const int q = lane >> 4, ln = lane & 15;

    f32x4 acc[2][2];
    mfma_layer<128, 128, 2, 2, PD>(wt1, b1, Xs, wave, lane, acc);
    #pragma unroll
    for (int mt = 0; mt < 2; mt++)
        #pragma unroll
        for (int nt = 0; nt < 2; nt++)
            #pragma unroll
            for (int r = 0; r < 4; r++)
                Hs[(mt * 16 + q * 4 + r) * PD + wave * 32 + nt * 16 + ln] =
                    f2bf(fmaxf(acc[mt][nt][r], 0.f));
    __syncthreads();

    f32x4 acc2[2][1];
    mfma_layer<128, 64, 1, 2, PD>(wt2, b2, Hs, wave, lane, acc2);
    #pragma unroll
    for (int mt = 0; mt < 2; mt++)
        #pragma unroll
        for (int r = 0; r < 4; r++)
            out[(size_t)(r0 + mt * 16 + q * 4 + r) * HD + wave * 16 + ln] =
                acc2[mt][0][r];
}

// ================= update kernel: OLD (bf16-accum read, fallback) ============
__global__ __launch_bounds__(256) void update_mfma(
    const float* __restrict__ ns, const ushort* __restrict__ S16,
    const unsigned* __restrict__ Mword,
    const ushort* __restrict__ wt1, const float* __restrict__ b1,
    const ushort* __restrict__ wt2, const float* __restrict__ b2,
    float* __restrict__ out)
{
    constexpr int D = 128, PD = D + 8;
    __shared__ __align__(16) ushort Xs[32 * PD];
    __shared__ __align__(16) ushort Hs[32 * PD];

    const int tid = threadIdx.x;
    const int r0  = blockIdx.x * 32;
    const float corr = 1e-16f * __expf(8.f * dec_f32(*Mword));

    for (int lin = tid; lin < 32 * 16; lin += 256) {
        int row = lin >> 4, c8 = (lin & 15) * 8;
        ushort tmp[8];
        if (c8 < 64) {
            ushort raw[8];
            *(uint4*)raw = *(const uint4*)(S16 + (size_t)(r0 + row) * HD + c8);
            #pragma unroll
            for (int j = 0; j < 8; j++)
                tmp[j] = f2bf(0.125f * __logf(bf2f(raw[j]) + corr));
        } else {
            #pragma unroll
            for (int j = 0; j < 8; j++)
                tmp[j] = f2bf(ns[(size_t)(r0 + row) * HD + (c8 - 64) + j]);
        }
        *(uint4*)(Xs + row * PD + c8) = *(uint4*)tmp;
    }
    __syncthreads();

    const int wave = tid >> 6, lane = tid & 63;
    const int q = lane >> 4, ln = lane & 15;

    f32x4 acc[2][2];
    mfma_layer<128, 128, 2, 2, PD>(wt1, b1, Xs, wave, lane, acc);
    #pragma unroll
    for (int mt = 0; mt < 2; mt++)
        #pragma unroll
        for (int nt = 0; nt < 2; nt++)
            #pragma unroll
            for (int r = 0; r < 4; r++)
                Hs[(mt * 16 + q * 4 + r) * PD + wave * 32 + nt * 16 + ln] =
                    f2bf(fmaxf(acc[mt][nt][r], 0.f));
    __syncthreads();

    f32x4 acc2[2][1];
    mfma_layer<128, 64, 1, 2, PD>(wt2, b2, Hs, wave, lane, acc2);
    #pragma unroll
    for (int mt = 0; mt < 2; mt++)
        #pragma unroll
        for (int r = 0; r < 4; r++)
            out[(size_t)(r0 + mt * 16 + q * 4 + r) * HD + wave * 16 + ln] =
                acc2[mt][0][r];
}

// ================= host =====================================================
extern "C" void kernel_launch(void* const* d_in, const int* in_sizes, int n_in,
                              void* d_out, int out_size, void* d_ws, size_t ws_size,
                              hipStream_t stream)
{
    const float* ns   = (const float*)d_in[0];
    const int*   idx0 = (const int*)d_in[1];
    const int*   idx1 = (const int*)d_in[2];
    const int*   idx2 = (const int*)d_in[3];
    const float* W[8] = { (const float*)d_in[4],  (const float*)d_in[6],
                          (const float*)d_in[8],  (const float*)d_in[10],
                          (const float*)d_in[12], (const float*)d_in[14],
                          (const float*)d_in[16], (const float*)d_in[18] };
    const float* B[8] = { (const float*)d_in[5],  (const float*)d_in[7],
                          (const float*)d_in[9],  (const float*)d_in[11],
                          (const float*)d_in[13], (const float*)d_in[15],
                          (const float*)d_in[17], (const float*)d_in[19] };
    static const int DIN[8]  = {128,128,128,128,192,192,128,128};
    static const int DOUT[8] = {128,128,128,128,192,192,128, 64};

    const int n0f = in_sizes[1];          // 600000 flat ints
    const int n1f = in_sizes[2];          // 600000
    const int n2f = in_sizes[3];          // 600000
    const int TOT = n0f + n1f + n2f;      // 1,800,000
    const int T0 = n0f / 2, T1 = n1f / 2, T2 = n2f / 3;

    size_t wtot = 0;
    for (int m = 0; m < 8; m++) wtot += (size_t)DIN[m] * DOUT[m];   // 360,448

    // ---- new-path workspace layout ----
    size_t oO     = 0;
    size_t oNs    = oO  + (size_t)TOT * HD * 2;                     // O2: 230.4 MB
    size_t oWT    = oNs + (size_t)NS_ELEMS * 2;                     // ns16: 25.6 MB
    size_t oPerm  = oWT + ((wtot * 2 + 255) & ~(size_t)255);
    size_t oStart = oPerm + (((size_t)TOT * 4 + 255) & ~(size_t)255);
    size_t oOff   = oStart + (((size_t)(NNODES + 1) * 4 + 255) & ~(size_t)255);
    size_t oPart  = oOff + (size_t)NNODES * 4;
    size_t oCnt   = oPart + 4096;
    size_t oMw    = oCnt + (size_t)NNODES * 4;
    size_t NEED   = oMw + 64;

    if (ws_size >= NEED) {
        // ================= perm / streaming wave path =================
        ushort*   O2    = (ushort*)d_ws;
        ushort*   ns16  = (ushort*)((char*)d_ws + oNs);
        ushort*   WTb   = (ushort*)((char*)d_ws + oWT);
        int*      perm  = (int*)((char*)d_ws + oPerm);
        int*      start = (int*)((char*)d_ws + oStart);
        int*      offp  = (int*)((char*)d_ws + oOff);
        int*      part  = (int*)((char*)d_ws + oPart);
        int*      cnt   = (int*)((char*)d_ws + oCnt);
        unsigned* Mw    = (unsigned*)((char*)d_ws + oMw);

        PrepArgs pa;
        int total = NS_ELEMS;
        ushort* wt[8];
        {
            ushort* p = WTb;
            for (int m = 0; m < 8; m++) {
                pa.src[m] = W[m];
                pa.dst[m] = p;  wt[m] = p;
                pa.din[m] = DIN[m]; pa.dout[m] = DOUT[m];
                pa.nelem[m] = DIN[m] * DOUT[m];
                p += pa.nelem[m];
                total += pa.nelem[m];
            }
        }

        hipMemsetAsync((char*)d_ws + oCnt, 0, (size_t)NNODES * 4 + 64, stream);
        prep_kernel<<<4096, 256, 0, stream>>>(ns, ns16, pa, total);

        const int NB   = (NNODES + 255) / 256;
        const int gTOT = (TOT + 255) / 256;
        hist_kernel<<<gTOT, 256, 0, stream>>>(idx0, idx1, idx2, n0f, n0f + n1f, TOT, cnt);
        scan1_kernel<<<NB, 256, 0, stream>>>(cnt, start, part, NNODES);
        scan2_kernel<<<1, 1024, 0, stream>>>(part, NB);
        scan3_kernel<<<NB, 256, 0, stream>>>(start, offp, part, NNODES, TOT);
        fill_perm<<<gTOT, 256, 0, stream>>>(idx0, idx1, idx2, n0f, n0f + n1f, TOT, offp, perm);

        // one wave (64 threads) per 16-tuple tile; no barriers, no persistence
        int nb0 = (T0 + 15) / 16, nb1 = (T1 + 15) / 16, nb2 = (T2 + 15) / 16;
        rel_wave<2><<<nb0, 64, 0, stream>>>(
            ns16, idx0, perm, wt[0], B[0], wt[1], B[1], O2, Mw, T0);
        rel_wave<2><<<nb1, 64, 0, stream>>>(
            ns16, idx1, perm + n0f, wt[2], B[2], wt[3], B[3], O2, Mw, T1);
        rel_wave<3><<<nb2, 64, 0, stream>>>(
            ns16, idx2, perm + n0f + n1f, wt[4], B[4], wt[5], B[5], O2, Mw, T2);

        update_lin<<<NNODES / 32, 256, 0, stream>>>(
            ns, O2, start, Mw, wt[6], B[6], wt[7], B[7], (float*)d_out);
    } else {
        // ================= fallback: atomic path =================
        ushort*   S16  = (ushort*)d_ws;
        size_t    offM = (size_t)NNODES * HD * sizeof(ushort);
        unsigned* Mw   = (unsigned*)((char*)d_ws + offM);
        ushort*   ns16 = (ushort*)((char*)d_ws + offM + 64);
        ushort*   WTb  = ns16 + (size_t)NS_ELEMS;

        PrepArgs pa;
        int total = NS_ELEMS;
        ushort* wt[8];
        {
            ushort* p = WTb;
            for (int m = 0; m < 8; m++) {
                pa.src[m] = W[m];
                pa.dst[m] = p;  wt[m] = p;
                pa.din[m] = DIN[m]; pa.dout[m] = DOUT[m];
                pa.nelem[m] = DIN[m] * DOUT[m];
                p += pa.nelem[m];
                total += pa.nelem[m];
            }
        }

        hipMemsetAsync(d_ws, 0, offM + 64, stream);
        prep_kernel<<<4096, 256, 0, stream>>>(ns, ns16, pa, total);

        rel_mfma<2><<<T0 / 32, 256, 0, stream>>>(ns16, idx0, wt[0], B[0], wt[1], B[1], S16, Mw);
        rel_mfma<2><<<T1 / 32, 256, 0, stream>>>(ns16, idx1, wt[2], B[2], wt[3], B[3], S16, Mw);
        rel_mfma<3><<<T2 / 32, 256, 0, stream>>>(ns16, idx2, wt[4], B[4], wt[5], B[5], S16, Mw);
        update_mfma<<<NNODES / 32, 256, 0, stream>>>(ns, S16, Mw, wt[6], B[6], wt[7], B[7],
                                                     (float*)d_out);
    }
}

// Round 10
// 763.057 us; speedup vs baseline: 1.3696x; 1.3696x over previous
//
#include <hip/hip_runtime.h>
#include <cstdint>

#define HD 64
#define NNODES 200000
#define NS_ELEMS (NNODES * HD)          // 12,800,000

typedef short bf8 __attribute__((ext_vector_type(8)));
typedef short s2v __attribute__((ext_vector_type(2)));
typedef float f32x4 __attribute__((ext_vector_type(4)));

// ---- order-preserving float <-> uint for atomicMax ----
__device__ __forceinline__ unsigned enc_f32(float f) {
    unsigned u = __float_as_uint(f);
    return (u & 0x80000000u) ? ~u : (u | 0x80000000u);
}
__device__ __forceinline__ float dec_f32(unsigned v) {
    return (v & 0x80000000u) ? __uint_as_float(v & 0x7fffffffu)
                             : __uint_as_float(~v);
}

// RNE float -> bf16 bits, and back
__device__ __forceinline__ ushort f2bf(float f) {
    unsigned u = __float_as_uint(f);
    return (ushort)((u + 0x7fffu + ((u >> 16) & 1u)) >> 16);
}
__device__ __forceinline__ float bf2f(ushort b) {
    return __uint_as_float(((unsigned)b) << 16);
}

// ---- packed 2x bf16 atomic add (fallback path only) ----
__device__ __forceinline__ void atom_pk_add_bf16(ushort* p, ushort lo, ushort hi) {
    s2v v; v[0] = (short)lo; v[1] = (short)hi;
#if __has_builtin(__builtin_amdgcn_flat_atomic_fadd_v2bf16)
    (void)__builtin_amdgcn_flat_atomic_fadd_v2bf16((s2v*)p, v);
#elif __has_builtin(__builtin_amdgcn_global_atomic_fadd_v2bf16)
    (void)__builtin_amdgcn_global_atomic_fadd_v2bf16(
        (__attribute__((address_space(1))) s2v*)p, v);
#else
    unsigned* a = (unsigned*)p;
    unsigned old = *a, assumed;
    do {
        assumed = old;
        float f0 = bf2f((ushort)(assumed & 0xffffu)) + bf2f(lo);
        float f1 = bf2f((ushort)(assumed >> 16))     + bf2f(hi);
        unsigned nv = (unsigned)f2bf(f0) | ((unsigned)f2bf(f1) << 16);
        old = atomicCAS(a, assumed, nv);
    } while (old != assumed);
#endif
}

// ================= prep: ns fp32->bf16; weights fp32 -> bf16 frag-linear =====
struct PrepArgs {
    const float* src[8];
    ushort*      dst[8];
    int din[8], dout[8], nelem[8];
};

__global__ __launch_bounds__(256) void prep_kernel(
    const float* __restrict__ ns, ushort* __restrict__ ns16, PrepArgs pa, int total)
{
    int stride = gridDim.x * 256;
    for (int i = blockIdx.x * 256 + threadIdx.x; i < total; i += stride) {
        if (i < NS_ELEMS) { ns16[i] = f2bf(ns[i]); continue; }
        int e = i - NS_ELEMS;
        #pragma unroll
        for (int m = 0; m < 8; m++) {
            if (e < pa.nelem[m]) {
                int din = pa.din[m], dout = pa.dout[m];
                int n = e / din, k = e - n * din;
                pa.dst[m][(k >> 5) * dout * 32 + n * 32 + (k & 31)] = f2bf(pa.src[m][e]);
                e = 0x7fffffff;
            } else {
                e -= pa.nelem[m];
            }
        }
    }
}

// ================= CSR build: hist -> scan -> perm ==========================
__global__ __launch_bounds__(256) void hist_kernel(
    const int* __restrict__ i0, const int* __restrict__ i1, const int* __restrict__ i2,
    int b1e, int b2e, int total, int* __restrict__ cnt)
{
    int s = blockIdx.x * 256 + threadIdx.x;
    if (s >= total) return;
    int node = (s < b1e) ? i0[s] : (s < b2e ? i1[s - b1e] : i2[s - b2e]);
    atomicAdd(&cnt[node], 1);
}

__global__ __launch_bounds__(256) void scan1_kernel(
    const int* __restrict__ cnt, int* __restrict__ startv,
    int* __restrict__ partials, int n)
{
    __shared__ int wsum[4];
    int i = blockIdx.x * 256 + threadIdx.x;
    int v = (i < n) ? cnt[i] : 0;
    int lane = threadIdx.x & 63, wid = threadIdx.x >> 6;
    int x = v;
    #pragma unroll
    for (int off = 1; off < 64; off <<= 1) {
        int y = __shfl_up(x, off);
        if (lane >= off) x += y;
    }
    if (lane == 63) wsum[wid] = x;
    __syncthreads();
    int woff = 0;
    for (int w = 0; w < wid; w++) woff += wsum[w];
    int incl = x + woff;
    if (i < n) startv[i] = incl - v;              // block-local exclusive
    if (threadIdx.x == 255) partials[blockIdx.x] = incl;
}

__global__ __launch_bounds__(1024) void scan2_kernel(int* __restrict__ partials, int nb)
{
    __shared__ int sh[1024];
    int t = threadIdx.x;
    int orig = (t < nb) ? partials[t] : 0;
    sh[t] = orig;
    __syncthreads();
    for (int off = 1; off < 1024; off <<= 1) {
        int v = (t >= off) ? sh[t - off] : 0;
        __syncthreads();
        sh[t] += v;
        __syncthreads();
    }
    if (t < nb) partials[t] = sh[t] - orig;       // exclusive
}

__global__ __launch_bounds__(256) void scan3_kernel(
    int* __restrict__ startv, int* __restrict__ offv,
    const int* __restrict__ partials, int n, int total)
{
    int i = blockIdx.x * 256 + threadIdx.x;
    if (i < n) {
        int s = startv[i] + partials[blockIdx.x];
        startv[i] = s;
        offv[i] = s;
    }
    if (i == 0) startv[n] = total;
}

// perm[s] = destination row of slot s (linear write; atomic only on hot cursors)
__global__ __launch_bounds__(256) void fill_perm(
    const int* __restrict__ i0, const int* __restrict__ i1, const int* __restrict__ i2,
    int b1e, int b2e, int total, int* __restrict__ offv, int* __restrict__ perm)
{
    int s = blockIdx.x * 256 + threadIdx.x;
    if (s >= total) return;
    int node = (s < b1e) ? i0[s] : (s < b2e ? i1[s - b1e] : i2[s - b2e]);
    perm[s] = atomicAdd(&offv[node], 1);
}

// ========= MFMA dense layer over an MT*16-row LDS tile (update/fallback) ====
template<int DIN, int DOUT, int NT, int MT, int PDIN>
__device__ __forceinline__ void mfma_layer(
    const ushort* __restrict__ WT, const float* __restrict__ bias,
    const ushort* __restrict__ Xs, int wave, int lane, f32x4 acc[MT][NT])
{
    constexpr int KS = DIN / 32;
    const int q = lane >> 4, ln = lane & 15;
    const int n0 = wave * NT * 16;
    bf8 bf[NT][KS];
    #pragma unroll
    for (int nt = 0; nt < NT; nt++) {
        float bv = bias[n0 + nt * 16 + ln];
        #pragma unroll
        for (int mt = 0; mt < MT; mt++)
            acc[mt][nt] = f32x4{bv, bv, bv, bv};
        #pragma unroll
        for (int ks = 0; ks < KS; ks++)
            bf[nt][ks] = *(const bf8*)(WT + (size_t)ks * DOUT * 32
                                          + (n0 + nt * 16 + ln) * 32 + q * 8);
    }
    #pragma unroll
    for (int mt = 0; mt < MT; mt++) {
        bf8 af[KS];
        #pragma unroll
        for (int ks = 0; ks < KS; ks++)
            af[ks] = *(const bf8*)(Xs + (mt * 16 + ln) * PDIN + ks * 32 + q * 8);
        #pragma unroll
        for (int ks = 0; ks < KS; ks++)
            #pragma unroll
            for (int nt = 0; nt < NT; nt++)
                acc[mt][nt] = __builtin_amdgcn_mfma_f32_16x16x32_bf16(
                    af[ks], bf[nt][ks], acc[mt][nt], 0, 0, 0);
    }
}

// ====== relation kernel: 4 INDEPENDENT waves/block, 32 tuples/wave ==========
// No __syncthreads anywhere: each wave owns a private LDS slice; wave-internal
// LDS ordering via s_waitcnt lgkmcnt(0) + sched_barrier (rule-18 pattern).
// Weight fragments batched per nt (bw[KS] then chain) so L2 latency overlaps;
// each fragment reused by 2 row-tiles (mt) = round-3's weight economy.
template<int A>
__global__ __launch_bounds__(256) void rel_wave32(
    const ushort* __restrict__ ns16, const int* __restrict__ idx,
    const int* __restrict__ perm,
    const ushort* __restrict__ wt1, const float* __restrict__ b1,
    const ushort* __restrict__ wt2, const float* __restrict__ b2,
    ushort* __restrict__ O2, unsigned* __restrict__ Mword,
    int ntiles, int Ttup)
{
    constexpr int D  = A * HD;
    constexpr int PD = D + 8;
    constexpr int NT = D / 16;             // wave covers ALL output cols
    constexpr int KS = D / 32;
    __shared__ __align__(16) ushort Hs[4][32 * PD];

    const int wid  = threadIdx.x >> 6;
    const int lane = threadIdx.x & 63;
    const int q = lane >> 4, ln = lane & 15;

    const int ti = blockIdx.x * 4 + wid;
    if (ti >= ntiles) return;              // no barriers: early-exit is safe
    const int t0 = ti * 32;
    ushort* hs = Hs[wid];

    // my two tuple rows: t0+ln (mt=0), t0+16+ln (mt=1); clamp tails
    int tr0 = t0 + ln;      if (tr0 >= Ttup) tr0 = Ttup - 1;
    int tr1 = t0 + 16 + ln; if (tr1 >= Ttup) tr1 = Ttup - 1;
    int nd0[A], nd1[A];
    #pragma unroll
    for (int s = 0; s < A; s++) {
        nd0[s] = idx[tr0 * A + s];
        nd1[s] = idx[tr1 * A + s];
    }

    // layer1 A-fragments straight from global (fragment bytes == node-row bytes)
    bf8 af[2][KS];
    #pragma unroll
    for (int ks = 0; ks < KS; ks++) {
        af[0][ks] = *(const bf8*)(ns16 + (size_t)nd0[ks >> 1] * HD
                                        + (ks & 1) * 32 + q * 8);
        af[1][ks] = *(const bf8*)(ns16 + (size_t)nd1[ks >> 1] * HD
                                        + (ks & 1) * 32 + q * 8);
    }

    // ---- layer1: batched weight loads, then chain; ReLU -> hs
    #pragma unroll
    for (int nt = 0; nt < NT; nt++) {
        const ushort* wp = wt1 + (size_t)(nt * 16 + ln) * 32 + q * 8;
        bf8 bw[KS];
        #pragma unroll
        for (int ks = 0; ks < KS; ks++)
            bw[ks] = *(const bf8*)(wp + (size_t)ks * D * 32);
        float bv = b1[nt * 16 + ln];
        f32x4 a0 = f32x4{bv, bv, bv, bv}, a1 = a0;
        #pragma unroll
        for (int ks = 0; ks < KS; ks++) {
            a0 = __builtin_amdgcn_mfma_f32_16x16x32_bf16(af[0][ks], bw[ks], a0, 0, 0, 0);
            a1 = __builtin_amdgcn_mfma_f32_16x16x32_bf16(af[1][ks], bw[ks], a1, 0, 0, 0);
        }
        #pragma unroll
        for (int r = 0; r < 4; r++) {
            hs[(q * 4 + r) * PD + nt * 16 + ln]      = f2bf(fmaxf(a0[r], 0.f));
            hs[(16 + q * 4 + r) * PD + nt * 16 + ln] = f2bf(fmaxf(a1[r], 0.f));
        }
    }
    asm volatile("s_waitcnt lgkmcnt(0)" ::: "memory");
    __builtin_amdgcn_sched_barrier(0);

    // layer2 A-fragments from hs (transpose via LDS)
    #pragma unroll
    for (int ks = 0; ks < KS; ks++) {
        af[0][ks] = *(const bf8*)(&hs[ln * PD + ks * 32 + q * 8]);
        af[1][ks] = *(const bf8*)(&hs[(16 + ln) * PD + ks * 32 + q * 8]);
    }
    asm volatile("s_waitcnt lgkmcnt(0)" ::: "memory");
    __builtin_amdgcn_sched_barrier(0);

    // ---- layer2 + exp staging back into hs, guarded max
    float mmax = -3.0e38f;
    #pragma unroll
    for (int nt = 0; nt < NT; nt++) {
        const ushort* wp = wt2 + (size_t)(nt * 16 + ln) * 32 + q * 8;
        bf8 bw[KS];
        #pragma unroll
        for (int ks = 0; ks < KS; ks++)
            bw[ks] = *(const bf8*)(wp + (size_t)ks * D * 32);
        float bv = b2[nt * 16 + ln];
        f32x4 a0 = f32x4{bv, bv, bv, bv}, a1 = a0;
        #pragma unroll
        for (int ks = 0; ks < KS; ks++) {
            a0 = __builtin_amdgcn_mfma_f32_16x16x32_bf16(af[0][ks], bw[ks], a0, 0, 0, 0);
            a1 = __builtin_amdgcn_mfma_f32_16x16x32_bf16(af[1][ks], bw[ks], a1, 0, 0, 0);
        }
        #pragma unroll
        for (int r = 0; r < 4; r++) {
            float o0 = a0[r], o1 = a1[r];
            if (t0 + q * 4 + r < Ttup)      mmax = fmaxf(mmax, o0);
            if (t0 + 16 + q * 4 + r < Ttup) mmax = fmaxf(mmax, o1);
            hs[(q * 4 + r) * PD + nt * 16 + ln]      = f2bf(__expf(8.f * o0));
            hs[(16 + q * 4 + r) * PD + nt * 16 + ln] = f2bf(__expf(8.f * o1));
        }
    }
    asm volatile("s_waitcnt lgkmcnt(0)" ::: "memory");
    __builtin_amdgcn_sched_barrier(0);

    // ---- scatter: full 128B rows -> O2[perm[slot]] (8 lanes x 16B per row)
    #pragma unroll
    for (int t = 0; t < 4 * A; t++) {
        int lin  = lane + t * 64;          // 0 .. 256*A-1 -> 32*A slots
        int slot = lin >> 3, part = lin & 7;
        int row  = slot / A, sub = slot - row * A;
        if (t0 + row < Ttup) {
            int p = perm[(t0 + row) * A + sub];
            *(uint4*)(O2 + (size_t)p * HD + part * 8) =
                *(const uint4*)(&hs[row * PD + sub * 64 + part * 8]);
        }
    }

    // wave max -> one atomic per wave
    #pragma unroll
    for (int off = 32; off; off >>= 1) mmax = fmaxf(mmax, __shfl_xor(mmax, off));
    if (lane == 0) atomicMax(Mword, enc_f32(mmax));
}

// ================= relation kernel: OLD (atomic scatter, fallback) ===========
template<int A>
__global__ __launch_bounds__(256) void rel_mfma(
    const ushort* __restrict__ ns16, const int* __restrict__ idx,
    const ushort* __restrict__ wt1, const float* __restrict__ b1,
    const ushort* __restrict__ wt2, const float* __restrict__ b2,
    ushort* __restrict__ S16, unsigned* __restrict__ Mword)
{
    constexpr int D  = A * HD;
    constexpr int PD = D + 8;
    constexpr int NT = D / 64;
    __shared__ __align__(16) ushort Xs[32 * PD];
    __shared__ __align__(16) ushort Hs[32 * PD];
    __shared__ int Is[32 * A];
    __shared__ float wred[4];

    const int tid = threadIdx.x;
    const int t0  = blockIdx.x * 32;

    if (tid < 32 * A) Is[tid] = idx[t0 * A + tid];
    for (int lin = tid; lin < 32 * A * 8; lin += 256) {
        int slot = lin >> 3, part = lin & 7;
        int node = idx[t0 * A + slot];
        int row = slot / A, sub = slot - row * A;
        *(uint4*)(Xs + row * PD + sub * 64 + part * 8) =
            *(const uint4*)(ns16 + (size_t)node * HD + part * 8);
    }
    __syncthreads();

    const int wave = tid >> 6, lane = tid & 63;
    const int q = lane >> 4, ln = lane & 15, n0 = wave * NT * 16;

    f32x4 acc[2][NT];
    mfma_layer<D, D, NT, 2, PD>(wt1, b1, Xs, wave, lane, acc);
    #pragma unroll
    for (int mt = 0; mt < 2; mt++)
        #pragma unroll
        for (int nt = 0; nt < NT; nt++)
            #pragma unroll
            for (int r = 0; r < 4; r++)
                Hs[(mt * 16 + q * 4 + r) * PD + n0 + nt * 16 + ln] =
                    f2bf(fmaxf(acc[mt][nt][r], 0.f));
    __syncthreads();
    mfma_layer<D, D, NT, 2, PD>(wt2, b2, Hs, wave, lane, acc);

    float m = -3.0e38f;
    const bool even = (ln & 1) == 0;
    #pragma unroll
    for (int mt = 0; mt < 2; mt++)
        #pragma unroll
        for (int nt = 0; nt < NT; nt++) {
            int colg = n0 + nt * 16 + ln;
            int sub  = colg >> 6;
            int featp = (colg & 63) & ~1;
            float e[4], p[4];
            #pragma unroll
            for (int r = 0; r < 4; r++) {
                float o = acc[mt][nt][r];
                m = fmaxf(m, o);
                e[r] = __expf(8.f * o);
            }
            #pragma unroll
            for (int r = 0; r < 4; r++) p[r] = __shfl_xor(e[r], 1);
            #pragma unroll
            for (int j = 0; j < 2; j++) {
                int r   = even ? j : (2 + j);
                int row = mt * 16 + q * 4 + r;
                int node = Is[row * A + sub];
                ushort lo = even ? f2bf(e[r]) : f2bf(p[r]);
                ushort hi = even ? f2bf(p[r]) : f2bf(e[r]);
                atom_pk_add_bf16(S16 + (size_t)node * HD + featp, lo, hi);
            }
        }
    #pragma unroll
    for (int off = 32; off; off >>= 1) m = fmaxf(m, __shfl_xor(m, off));
    if (lane == 0) wred[wave] = m;
    __syncthreads();
    if (tid == 0)
        atomicMax(Mword, enc_f32(fmaxf(fmaxf(wred[0], wred[1]),
                                       fmaxf(wred[2], wred[3]))));
}

// ===== update kernel: contiguous segment reduce (streaming) + MFMA ==========
__global__ __launch_bounds__(256) void update_lin(
    const float* __restrict__ ns, const ushort* __restrict__ O2,
    const int* __restrict__ startv,
    const unsigned* __restrict__ Mword,
    const ushort* __restrict__ wt1, const float* __restrict__ b1,
    const ushort* __restrict__ wt2, const float* __restrict__ b2,
    float* __restrict__ out)
{
    constexpr int D = 128, PD = D + 8;
    __shared__ __align__(16) ushort Xs[32 * PD];
    __shared__ __align__(16) ushort Hs[32 * PD];

    const int tid = threadIdx.x;
    const int r0  = blockIdx.x * 32;
    const float corr = 1e-16f * __expf(8.f * dec_f32(*Mword));

    // ns half: rows 0..31, cols 64..127
    for (int lin = tid; lin < 32 * 8; lin += 256) {
        int row = lin >> 3, p8 = (lin & 7) * 8;
        const float* src = ns + (size_t)(r0 + row) * HD + p8;
        float4 a = *(const float4*)src;
        float4 b = *(const float4*)(src + 4);
        ushort tmp[8] = { f2bf(a.x), f2bf(a.y), f2bf(a.z), f2bf(a.w),
                          f2bf(b.x), f2bf(b.y), f2bf(b.z), f2bf(b.w) };
        *(uint4*)(Xs + row * PD + 64 + p8) = *(uint4*)tmp;
    }

    // segmented reduce over CONTIGUOUS rows: thread t owns (node tid>>3, feats (tid&7)*8)
    {
        const int row = tid >> 3, f0 = (tid & 7) * 8;
        const int s0 = startv[r0 + row];
        const int s1 = startv[r0 + row + 1];
        float sum[8] = {0.f, 0.f, 0.f, 0.f, 0.f, 0.f, 0.f, 0.f};
        int k = s0;
        for (; k + 1 < s1; k += 2) {
            ushort ra[8], rb[8];
            *(uint4*)ra = *(const uint4*)(O2 + (size_t)k * HD + f0);
            *(uint4*)rb = *(const uint4*)(O2 + (size_t)(k + 1) * HD + f0);
            #pragma unroll
            for (int j = 0; j < 8; j++) sum[j] += bf2f(ra[j]) + bf2f(rb[j]);
        }
        if (k < s1) {
            ushort ra[8];
            *(uint4*)ra = *(const uint4*)(O2 + (size_t)k * HD + f0);
            #pragma unroll
            for (int j = 0; j < 8; j++) sum[j] += bf2f(ra[j]);
        }
        ushort tmp[8];
        #pragma unroll
        for (int j = 0; j < 8; j++)
            tmp[j] = f2bf(0.125f * __logf(sum[j] + corr));
        *(uint4*)(Xs + row * PD + f0) = *(uint4*)tmp;
    }
    __syncthreads();

    const int wave = tid >> 6, lane = tid & 63;
    const int q = lane >> 4, ln = lane & 15;

    f32x4 acc[2][2];
    mfma_layer<128, 128, 2, 2, PD>(wt1, b1, Xs, wave, lane, acc);
    #pragma unroll
    for (int mt = 0; mt < 2; mt++)
        #pragma unroll
        for (int nt = 0; nt < 2; nt++)
            #pragma unroll
            for (int r = 0; r < 4; r++)
                Hs[(mt * 16 + q * 4 + r) * PD + wave * 32 + nt * 16 + ln] =
                    f2bf(fmaxf(acc[mt][nt][r], 0.f));
    __syncthreads();

    f32x4 acc2[2][1];
    mfma_layer<128, 64, 1, 2, PD>(wt2, b2, Hs, wave, lane, acc2);
    #pragma unroll
    for (int mt = 0; mt < 2; mt++)
        #pragma unroll
        for (int r = 0; r < 4; r++)
            out[(size_t)(r0 + mt * 16 + q * 4 + r) * HD + wave * 16 + ln] =
                acc2[mt][0][r];
}

// ================= update kernel: OLD (bf16-accum read, fallback) ============
__global__ __launch_bounds__(256) void update_mfma(
    const float* __restrict__ ns, const ushort* __restrict__ S16,
    const unsigned* __restrict__ Mword,
    const ushort* __restrict__ wt1, const float* __restrict__ b1,
    const ushort* __restrict__ wt2, const float* __restrict__ b2,
    float* __restrict__ out)
{
    constexpr int D = 128, PD = D + 8;
    __shared__ __align__(16) ushort Xs[32 * PD];
    __shared__ __align__(16) ushort Hs[32 * PD];

    const int tid = threadIdx.x;
    const int r0  = blockIdx.x * 32;
    const float corr = 1e-16f * __expf(8.f * dec_f32(*Mword));

    for (int lin = tid; lin < 32 * 16; lin += 256) {
        int row = lin >> 4, c8 = (lin & 15) * 8;
        ushort tmp[8];
        if (c8 < 64) {
            ushort raw[8];
            *(uint4*)raw = *(const uint4*)(S16 + (size_t)(r0 + row) * HD + c8);
            #pragma unroll
            for (int j = 0; j < 8; j++)
                tmp[j] = f2bf(0.125f * __logf(bf2f(raw[j]) + corr));
        } else {
            #pragma unroll
            for (int j = 0; j < 8; j++)
                tmp[j] = f2bf(ns[(size_t)(r0 + row) * HD + (c8 - 64) + j]);
        }
        *(uint4*)(Xs + row * PD + c8) = *(uint4*)tmp;
    }
    __syncthreads();

    const int wave = tid >> 6, lane = tid & 63;
    const int q = lane >> 4, ln = lane & 15;

    f32x4 acc[2][2];
    mfma_layer<128, 128, 2, 2, PD>(wt1, b1, Xs, wave, lane, acc);
    #pragma unroll
    for (int mt = 0; mt < 2; mt++)
        #pragma unroll
        for (int nt = 0; nt < 2; nt++)
            #pragma unroll
            for (int r = 0; r < 4; r++)
                Hs[(mt * 16 + q * 4 + r) * PD + wave * 32 + nt * 16 + ln] =
                    f2bf(fmaxf(acc[mt][nt][r], 0.f));
    __syncthreads();

    f32x4 acc2[2][1];
    mfma_layer<128, 64, 1, 2, PD>(wt2, b2, Hs, wave, lane, acc2);
    #pragma unroll
    for (int mt = 0; mt < 2; mt++)
        #pragma unroll
        for (int r = 0; r < 4; r++)
            out[(size_t)(r0 + mt * 16 + q * 4 + r) * HD + wave * 16 + ln] =
                acc2[mt][0][r];
}

// ================= host =====================================================
extern "C" void kernel_launch(void* const* d_in, const int* in_sizes, int n_in,
                              void* d_out, int out_size, void* d_ws, size_t ws_size,
                              hipStream_t stream)
{
    const float* ns   = (const float*)d_in[0];
    const int*   idx0 = (const int*)d_in[1];
    const int*   idx1 = (const int*)d_in[2];
    const int*   idx2 = (const int*)d_in[3];
    const float* W[8] = { (const float*)d_in[4],  (const float*)d_in[6],
                          (const float*)d_in[8],  (const float*)d_in[10],
                          (const float*)d_in[12], (const float*)d_in[14],
                          (const float*)d_in[16], (const float*)d_in[18] };
    const float* B[8] = { (const float*)d_in[5],  (const float*)d_in[7],
                          (const float*)d_in[9],  (const float*)d_in[11],
                          (const float*)d_in[13], (const float*)d_in[15],
                          (const float*)d_in[17], (const float*)d_in[19] };
    static const int DIN[8]  = {128,128,128,128,192,192,128,128};
    static const int DOUT[8] = {128,128,128,128,192,192,128, 64};

    const int n0f = in_sizes[1];          // 600000 flat ints
    const int n1f = in_sizes[2];          // 600000
    const int n2f = in_sizes[3];          // 600000
    const int TOT = n0f + n1f + n2f;      // 1,800,000
    const int T0 = n0f / 2, T1 = n1f / 2, T2 = n2f / 3;

    size_t wtot = 0;
    for (int m = 0; m < 8; m++) wtot += (size_t)DIN[m] * DOUT[m];   // 360,448

    // ---- new-path workspace layout ----
    size_t oO     = 0;
    size_t oNs    = oO  + (size_t)TOT * HD * 2;                     // O2: 230.4 MB
    size_t oWT    = oNs + (size_t)NS_ELEMS * 2;                     // ns16: 25.6 MB
    size_t oPerm  = oWT + ((wtot * 2 + 255) & ~(size_t)255);
    size_t oStart = oPerm + (((size_t)TOT * 4 + 255) & ~(size_t)255);
    size_t oOff   = oStart + (((size_t)(NNODES + 1) * 4 + 255) & ~(size_t)255);
    size_t oPart  = oOff + (size_t)NNODES * 4;
    size_t oCnt   = oPart + 4096;
    size_t oMw    = oCnt + (size_t)NNODES * 4;
    size_t NEED   = oMw + 64;

    if (ws_size >= NEED) {
        // ================= perm / streaming wave path =================
        ushort*   O2    = (ushort*)d_ws;
        ushort*   ns16  = (ushort*)((char*)d_ws + oNs);
        ushort*   WTb   = (ushort*)((char*)d_ws + oWT);
        int*      perm  = (int*)((char*)d_ws + oPerm);
        int*      start = (int*)((char*)d_ws + oStart);
        int*      offp  = (int*)((char*)d_ws + oOff);
        int*      part  = (int*)((char*)d_ws + oPart);
        int*      cnt   = (int*)((char*)d_ws + oCnt);
        unsigned* Mw    = (unsigned*)((char*)d_ws + oMw);

        PrepArgs pa;
        int total = NS_ELEMS;
        ushort* wt[8];
        {
            ushort* p = WTb;
            for (int m = 0; m < 8; m++) {
                pa.src[m] = W[m];
                pa.dst[m] = p;  wt[m] = p;
                pa.din[m] = DIN[m]; pa.dout[m] = DOUT[m];
                pa.nelem[m] = DIN[m] * DOUT[m];
                p += pa.nelem[m];
                total += pa.nelem[m];
            }
        }

        hipMemsetAsync((char*)d_ws + oCnt, 0, (size_t)NNODES * 4 + 64, stream);
        prep_kernel<<<4096, 256, 0, stream>>>(ns, ns16, pa, total);

        const int NB   = (NNODES + 255) / 256;
        const int gTOT = (TOT + 255) / 256;
        hist_kernel<<<gTOT, 256, 0, stream>>>(idx0, idx1, idx2, n0f, n0f + n1f, TOT, cnt);
        scan1_kernel<<<NB, 256, 0, stream>>>(cnt, start, part, NNODES);
        scan2_kernel<<<1, 1024, 0, stream>>>(part, NB);
        scan3_kernel<<<NB, 256, 0, stream>>>(start, offp, part, NNODES, TOT);
        fill_perm<<<gTOT, 256, 0, stream>>>(idx0, idx1, idx2, n0f, n0f + n1f, TOT, offp, perm);

        // 4 independent waves per block, 32 tuples per wave, no barriers
        int ntile0 = (T0 + 31) / 32, ntile1 = (T1 + 31) / 32, ntile2 = (T2 + 31) / 32;
        int nb0 = (ntile0 + 3) / 4, nb1 = (ntile1 + 3) / 4, nb2 = (ntile2 + 3) / 4;
        rel_wave32<2><<<nb0, 256, 0, stream>>>(
            ns16, idx0, perm, wt[0], B[0], wt[1], B[1], O2, Mw, ntile0, T0);
        rel_wave32<2><<<nb1, 256, 0, stream>>>(
            ns16, idx1, perm + n0f, wt[2], B[2], wt[3], B[3], O2, Mw, ntile1, T1);
        rel_wave32<3><<<nb2, 256, 0, stream>>>(
            ns16, idx2, perm + n0f + n1f, wt[4], B[4], wt[5], B[5], O2, Mw, ntile2, T2);

        update_lin<<<NNODES / 32, 256, 0, stream>>>(
            ns, O2, start, Mw, wt[6], B[6], wt[7], B[7], (float*)d_out);
    } else {
        // ================= fallback: atomic path =================
        ushort*   S16  = (ushort*)d_ws;
        size_t    offM = (size_t)NNODES * HD * sizeof(ushort);
        unsigned* Mw   = (unsigned*)((char*)d_ws + offM);
        ushort*   ns16 = (ushort*)((char*)d_ws + offM + 64);
        ushort*   WTb  = ns16 + (size_t)NS_ELEMS;

        PrepArgs pa;
        int total = NS_ELEMS;
        ushort* wt[8];
        {
            ushort* p = WTb;
            for (int m = 0; m < 8; m++) {
                pa.src[m] = W[m];
                pa.dst[m] = p;  wt[m] = p;
                pa.din[m] = DIN[m]; pa.dout[m] = DOUT[m];
                pa.nelem[m] = DIN[m] * DOUT[m];
                p += pa.nelem[m];
                total += pa.nelem[m];
            }
        }

        hipMemsetAsync(d_ws, 0, offM + 64, stream);
        prep_kernel<<<4096, 256, 0, stream>>>(ns, ns16, pa, total);

        rel_mfma<2><<<T0 / 32, 256, 0, stream>>>(ns16, idx0, wt[0], B[0], wt[1], B[1], S16, Mw);
        rel_mfma<2><<<T1 / 32, 256, 0, stream>>>(ns16, idx1, wt[2], B[2], wt[3], B[3], S16, Mw);
        rel_mfma<3><<<T2 / 32, 256, 0, stream>>>(ns16, idx2, wt[4], B[4], wt[5], B[5], S16, Mw);
        update_mfma<<<NNODES / 32, 256, 0, stream>>>(ns, S16, Mw, wt[6], B[6], wt[7], B[7],
                                                     (float*)d_out);
    }
}

// Round 12
// 564.650 us; speedup vs baseline: 1.8509x; 1.3514x over previous
//
#include <hip/hip_runtime.h>
#include <cstdint>

#define HD 64
#define NNODES 200000
#define NS_ELEMS (NNODES * HD)          // 12,800,000

typedef short bf8 __attribute__((ext_vector_type(8)));
typedef short s2v __attribute__((ext_vector_type(2)));
typedef float f32x4 __attribute__((ext_vector_type(4)));

// ---- order-preserving float <-> uint for atomicMax ----
__device__ __forceinline__ unsigned enc_f32(float f) {
    unsigned u = __float_as_uint(f);
    return (u & 0x80000000u) ? ~u : (u | 0x80000000u);
}
__device__ __forceinline__ float dec_f32(unsigned v) {
    return (v & 0x80000000u) ? __uint_as_float(v & 0x7fffffffu)
                             : __uint_as_float(~v);
}

// RNE float -> bf16 bits, and back
__device__ __forceinline__ ushort f2bf(float f) {
    unsigned u = __float_as_uint(f);
    return (ushort)((u + 0x7fffu + ((u >> 16) & 1u)) >> 16);
}
__device__ __forceinline__ float bf2f(ushort b) {
    return __uint_as_float(((unsigned)b) << 16);
}

// ---- packed 2x bf16 atomic add (fallback path only) ----
__device__ __forceinline__ void atom_pk_add_bf16(ushort* p, ushort lo, ushort hi) {
    s2v v; v[0] = (short)lo; v[1] = (short)hi;
#if __has_builtin(__builtin_amdgcn_flat_atomic_fadd_v2bf16)
    (void)__builtin_amdgcn_flat_atomic_fadd_v2bf16((s2v*)p, v);
#elif __has_builtin(__builtin_amdgcn_global_atomic_fadd_v2bf16)
    (void)__builtin_amdgcn_global_atomic_fadd_v2bf16(
        (__attribute__((address_space(1))) s2v*)p, v);
#else
    unsigned* a = (unsigned*)p;
    unsigned old = *a, assumed;
    do {
        assumed = old;
        float f0 = bf2f((ushort)(assumed & 0xffffu)) + bf2f(lo);
        float f1 = bf2f((ushort)(assumed >> 16))     + bf2f(hi);
        unsigned nv = (unsigned)f2bf(f0) | ((unsigned)f2bf(f1) << 16);
        old = atomicCAS(a, assumed, nv);
    } while (old != assumed);
#endif
}

// ====== prep: ns fp32->bf16; weights fp32 -> bf16 frag-linear; + hist =======
struct PrepArgs {
    const float* src[8];
    ushort*      dst[8];
    int din[8], dout[8], nelem[8];
};

__global__ __launch_bounds__(256) void prep_kernel(
    const float* __restrict__ ns, ushort* __restrict__ ns16, PrepArgs pa, int total,
    const int* __restrict__ i0, const int* __restrict__ i1, const int* __restrict__ i2,
    int b1e, int b2e, int histBase, int* __restrict__ cnt)
{
    int stride = gridDim.x * 256;
    for (int i = blockIdx.x * 256 + threadIdx.x; i < total; i += stride) {
        if (i >= histBase) {
            // fused histogram over all flat idx entries
            int s = i - histBase;
            int node = (s < b1e) ? i0[s] : (s < b2e ? i1[s - b1e] : i2[s - b2e]);
            atomicAdd(&cnt[node], 1);
            continue;
        }
        if (i < NS_ELEMS) { ns16[i] = f2bf(ns[i]); continue; }
        int e = i - NS_ELEMS;
        #pragma unroll
        for (int m = 0; m < 8; m++) {
            if (e < pa.nelem[m]) {
                int din = pa.din[m], dout = pa.dout[m];
                int n = e / din, k = e - n * din;
                pa.dst[m][(k >> 5) * dout * 32 + n * 32 + (k & 31)] = f2bf(pa.src[m][e]);
                e = 0x7fffffff;
            } else {
                e -= pa.nelem[m];
            }
        }
    }
}

// ================= CSR build: scan -> perm ==================================
__global__ __launch_bounds__(256) void scan1_kernel(
    const int* __restrict__ cnt, int* __restrict__ startv,
    int* __restrict__ partials, int n)
{
    __shared__ int wsum[4];
    int i = blockIdx.x * 256 + threadIdx.x;
    int v = (i < n) ? cnt[i] : 0;
    int lane = threadIdx.x & 63, wid = threadIdx.x >> 6;
    int x = v;
    #pragma unroll
    for (int off = 1; off < 64; off <<= 1) {
        int y = __shfl_up(x, off);
        if (lane >= off) x += y;
    }
    if (lane == 63) wsum[wid] = x;
    __syncthreads();
    int woff = 0;
    for (int w = 0; w < wid; w++) woff += wsum[w];
    int incl = x + woff;
    if (i < n) startv[i] = incl - v;              // block-local exclusive
    if (threadIdx.x == 255) partials[blockIdx.x] = incl;
}

__global__ __launch_bounds__(1024) void scan2_kernel(int* __restrict__ partials, int nb)
{
    __shared__ int sh[1024];
    int t = threadIdx.x;
    int orig = (t < nb) ? partials[t] : 0;
    sh[t] = orig;
    __syncthreads();
    for (int off = 1; off < 1024; off <<= 1) {
        int v = (t >= off) ? sh[t - off] : 0;
        __syncthreads();
        sh[t] += v;
        __syncthreads();
    }
    if (t < nb) partials[t] = sh[t] - orig;       // exclusive
}

__global__ __launch_bounds__(256) void scan3_kernel(
    int* __restrict__ startv, int* __restrict__ offv,
    const int* __restrict__ partials, int n, int total)
{
    int i = blockIdx.x * 256 + threadIdx.x;
    if (i < n) {
        int s = startv[i] + partials[blockIdx.x];
        startv[i] = s;
        offv[i] = s;
    }
    if (i == 0) startv[n] = total;
}

// perm[s] = destination row of slot s (linear write; atomic only on hot cursors)
__global__ __launch_bounds__(256) void fill_perm(
    const int* __restrict__ i0, const int* __restrict__ i1, const int* __restrict__ i2,
    int b1e, int b2e, int total, int* __restrict__ offv, int* __restrict__ perm)
{
    int s = blockIdx.x * 256 + threadIdx.x;
    if (s >= total) return;
    int node = (s < b1e) ? i0[s] : (s < b2e ? i1[s - b1e] : i2[s - b2e]);
    perm[s] = atomicAdd(&offv[node], 1);
}

// ================= one MFMA dense layer over a 32-row LDS tile ===============
template<int DIN, int DOUT, int NT, int PDIN>
__device__ __forceinline__ void mfma_layer(
    const ushort* __restrict__ WT, const float* __restrict__ bias,
    const ushort* __restrict__ Xs, int wave, int lane, f32x4 acc[2][NT])
{
    constexpr int KS = DIN / 32;
    const int q = lane >> 4, ln = lane & 15;
    const int n0 = wave * NT * 16;
    bf8 bf[NT][KS];
    #pragma unroll
    for (int nt = 0; nt < NT; nt++) {
        float bv = bias[n0 + nt * 16 + ln];
        acc[0][nt] = f32x4{bv, bv, bv, bv};
        acc[1][nt] = f32x4{bv, bv, bv, bv};
        #pragma unroll
        for (int ks = 0; ks < KS; ks++)
            bf[nt][ks] = *(const bf8*)(WT + (size_t)ks * DOUT * 32
                                          + (n0 + nt * 16 + ln) * 32 + q * 8);
    }
    #pragma unroll
    for (int mt = 0; mt < 2; mt++) {
        bf8 af[KS];
        #pragma unroll
        for (int ks = 0; ks < KS; ks++)
            af[ks] = *(const bf8*)(Xs + (mt * 16 + ln) * PDIN + ks * 32 + q * 8);
        #pragma unroll
        for (int ks = 0; ks < KS; ks++)
            #pragma unroll
            for (int nt = 0; nt < NT; nt++)
                acc[mt][nt] = __builtin_amdgcn_mfma_f32_16x16x32_bf16(
                    af[ks], bf[nt][ks], acc[mt][nt], 0, 0, 0);
    }
}

// ====== relation kernel: round-3 exact (verified best configuration) ========
template<int A>
__global__ __launch_bounds__(256) void rel_mfma_pp(
    const ushort* __restrict__ ns16, const int* __restrict__ idx,
    const int* __restrict__ perm,
    const ushort* __restrict__ wt1, const float* __restrict__ b1,
    const ushort* __restrict__ wt2, const float* __restrict__ b2,
    ushort* __restrict__ O2, unsigned* __restrict__ Mword, int ntiles)
{
    constexpr int D  = A * HD;
    constexpr int PD = D + 8;
    constexpr int NT = D / 64;
    __shared__ __align__(16) ushort Xs[2][32 * PD];
    __shared__ __align__(16) ushort Hs[32 * PD];
    __shared__ int Pr[2][32 * A];
    __shared__ float wred[4];

    const int tid  = threadIdx.x;
    const int wave = tid >> 6, lane = tid & 63;
    const int q = lane >> 4, ln = lane & 15, n0 = wave * NT * 16;

    uint4 greg[A];
    int   pv = 0;
    float mblk = -3.0e38f;

    int ti = blockIdx.x;
    if (ti < ntiles) {
        int t0 = ti * 32;
        #pragma unroll
        for (int k = 0; k < A; k++) {
            int j = tid + k * 256;
            int slot = j >> 3, part = j & 7;
            int node = idx[t0 * A + slot];
            greg[k] = *(const uint4*)(ns16 + (size_t)node * HD + part * 8);
        }
        if (tid < 32 * A) pv = perm[t0 * A + tid];
        #pragma unroll
        for (int k = 0; k < A; k++) {
            int j = tid + k * 256;
            int slot = j >> 3, part = j & 7;
            int row = slot / A, sub = slot - row * A;
            *(uint4*)(&Xs[0][row * PD + sub * 64 + part * 8]) = greg[k];
        }
        if (tid < 32 * A) Pr[0][tid] = pv;
        __syncthreads();

        int cur = 0;
        for (;;) {
            int tn = ti + gridDim.x;
            bool has_next = tn < ntiles;
            if (has_next) {
                int t0n = tn * 32;
                #pragma unroll
                for (int k = 0; k < A; k++) {
                    int j = tid + k * 256;
                    int slot = j >> 3, part = j & 7;
                    int node = idx[t0n * A + slot];
                    greg[k] = *(const uint4*)(ns16 + (size_t)node * HD + part * 8);
                }
                if (tid < 32 * A) pv = perm[t0n * A + tid];
            }

            f32x4 acc[2][NT];
            mfma_layer<D, D, NT, PD>(wt1, b1, Xs[cur], wave, lane, acc);
            #pragma unroll
            for (int mt = 0; mt < 2; mt++)
                #pragma unroll
                for (int nt = 0; nt < NT; nt++)
                    #pragma unroll
                    for (int r = 0; r < 4; r++)
                        Hs[(mt * 16 + q * 4 + r) * PD + n0 + nt * 16 + ln] =
                            f2bf(fmaxf(acc[mt][nt][r], 0.f));
            __syncthreads();                       // (1) Hs ready for layer2
            mfma_layer<D, D, NT, PD>(wt2, b2, Hs, wave, lane, acc);
            __syncthreads();                       // (2) Hs reads done

            #pragma unroll
            for (int mt = 0; mt < 2; mt++)
                #pragma unroll
                for (int nt = 0; nt < NT; nt++) {
                    int colg = n0 + nt * 16 + ln;
                    #pragma unroll
                    for (int r = 0; r < 4; r++) {
                        float o = acc[mt][nt][r];
                        mblk = fmaxf(mblk, o);
                        Hs[(mt * 16 + q * 4 + r) * PD + colg] = f2bf(__expf(8.f * o));
                    }
                }
            __syncthreads();                       // (3) exp rows ready

            #pragma unroll
            for (int k = 0; k < A; k++) {
                int j = tid + k * 256;
                int slot = j >> 3, part = j & 7;
                int row = slot / A, sub = slot - row * A;
                *(uint4*)(O2 + (size_t)Pr[cur][slot] * HD + part * 8) =
                    *(const uint4*)(&Hs[row * PD + sub * 64 + part * 8]);
            }

            if (!has_next) break;

            __syncthreads();                       // (4) Hs scatter-reads done
            int nxt = cur ^ 1;
            #pragma unroll
            for (int k = 0; k < A; k++) {
                int j = tid + k * 256;
                int slot = j >> 3, part = j & 7;
                int row = slot / A, sub = slot - row * A;
                *(uint4*)(&Xs[nxt][row * PD + sub * 64 + part * 8]) = greg[k];
            }
            if (tid < 32 * A) Pr[nxt][tid] = pv;
            __syncthreads();                       // (5) Xs[nxt]/Pr[nxt] ready
            cur = nxt;
            ti = tn;
        }
    }

    #pragma unroll
    for (int off = 32; off; off >>= 1) mblk = fmaxf(mblk, __shfl_xor(mblk, off));
    if (lane == 0) wred[wave] = mblk;
    __syncthreads();
    if (tid == 0)
        atomicMax(Mword, enc_f32(fmaxf(fmaxf(wred[0], wred[1]),
                                       fmaxf(wred[2], wred[3]))));
}

// ================= relation kernel: OLD (atomic scatter, fallback) ===========
template<int A>
__global__ __launch_bounds__(256) void rel_mfma(
    const ushort* __restrict__ ns16, const int* __restrict__ idx,
    const ushort* __restrict__ wt1, const float* __restrict__ b1,
    const ushort* __restrict__ wt2, const float* __restrict__ b2,
    ushort* __restrict__ S16, unsigned* __restrict__ Mword)
{
    constexpr int D  = A * HD;
    constexpr int PD = D + 8;
    constexpr int NT = D / 64;
    __shared__ __align__(16) ushort Xs[32 * PD];
    __shared__ __align__(16) ushort Hs[32 * PD];
    __shared__ int Is[32 * A];
    __shared__ float wred[4];

    const int tid = threadIdx.x;
    const int t0  = blockIdx.x * 32;

    if (tid < 32 * A) Is[tid] = idx[t0 * A + tid];
    for (int lin = tid; lin < 32 * A * 8; lin += 256) {
        int slot = lin >> 3, part = lin & 7;
        int node = idx[t0 * A + slot];
        int row = slot / A, sub = slot - row * A;
        *(uint4*)(Xs + row * PD + sub * 64 + part * 8) =
            *(const uint4*)(ns16 + (size_t)node * HD + part * 8);
    }
    __syncthreads();

    const int wave = tid >> 6, lane = tid & 63;
    const int q = lane >> 4, ln = lane & 15, n0 = wave * NT * 16;

    f32x4 acc[2][NT];
    mfma_layer<D, D, NT, PD>(wt1, b1, Xs, wave, lane, acc);
    #pragma unroll
    for (int mt = 0; mt < 2; mt++)
        #pragma unroll
        for (int nt = 0; nt < NT; nt++)
            #pragma unroll
            for (int r = 0; r < 4; r++)
                Hs[(mt * 16 + q * 4 + r) * PD + n0 + nt * 16 + ln] =
                    f2bf(fmaxf(acc[mt][nt][r], 0.f));
    __syncthreads();
    mfma_layer<D, D, NT, PD>(wt2, b2, Hs, wave, lane, acc);

    float m = -3.0e38f;
    const bool even = (ln & 1) == 0;
    #pragma unroll
    for (int mt = 0; mt < 2; mt++)
        #pragma unroll
        for (int nt = 0; nt < NT; nt++) {
            int colg = n0 + nt * 16 + ln;
            int sub  = colg >> 6;
            int featp = (colg & 63) & ~1;
            float e[4], p[4];
            #pragma unroll
            for (int r = 0; r < 4; r++) {
                float o = acc[mt][nt][r];
                m = fmaxf(m, o);
                e[r] = __expf(8.f * o);
            }
            #pragma unroll
            for (int r = 0; r < 4; r++) p[r] = __shfl_xor(e[r], 1);
            #pragma unroll
            for (int j = 0; j < 2; j++) {
                int r   = even ? j : (2 + j);
                int row = mt * 16 + q * 4 + r;
                int node = Is[row * A + sub];
                ushort lo = even ? f2bf(e[r]) : f2bf(p[r]);
                ushort hi = even ? f2bf(p[r]) : f2bf(e[r]);
                atom_pk_add_bf16(S16 + (size_t)node * HD + featp, lo, hi);
            }
        }
    #pragma unroll
    for (int off = 32; off; off >>= 1) m = fmaxf(m, __shfl_xor(m, off));
    if (lane == 0) wred[wave] = m;
    __syncthreads();
    if (tid == 0)
        atomicMax(Mword, enc_f32(fmaxf(fmaxf(wred[0], wred[1]),
                                       fmaxf(wred[2], wred[3]))));
}

// ===== update kernel: contiguous segment reduce (streaming) + MFMA ==========
__global__ __launch_bounds__(256) void update_lin(
    const float* __restrict__ ns, const ushort* __restrict__ O2,
    const int* __restrict__ startv,
    const unsigned* __restrict__ Mword,
    const ushort* __restrict__ wt1, const float* __restrict__ b1,
    const ushort* __restrict__ wt2, const float* __restrict__ b2,
    float* __restrict__ out)
{
    constexpr int D = 128, PD = D + 8;
    __shared__ __align__(16) ushort Xs[32 * PD];
    __shared__ __align__(16) ushort Hs[32 * PD];

    const int tid = threadIdx.x;
    const int r0  = blockIdx.x * 32;
    const float corr = 1e-16f * __expf(8.f * dec_f32(*Mword));

    // ns half: rows 0..31, cols 64..127
    for (int lin = tid; lin < 32 * 8; lin += 256) {
        int row = lin >> 3, p8 = (lin & 7) * 8;
        const float* src = ns + (size_t)(r0 + row) * HD + p8;
        float4 a = *(const float4*)src;
        float4 b = *(const float4*)(src + 4);
        ushort tmp[8] = { f2bf(a.x), f2bf(a.y), f2bf(a.z), f2bf(a.w),
                          f2bf(b.x), f2bf(b.y), f2bf(b.z), f2bf(b.w) };
        *(uint4*)(Xs + row * PD + 64 + p8) = *(uint4*)tmp;
    }

    // segmented reduce over CONTIGUOUS rows
    {
        const int row = tid >> 3, f0 = (tid & 7) * 8;
        const int s0 = startv[r0 + row];
        const int s1 = startv[r0 + row + 1];
        float sum[8] = {0.f, 0.f, 0.f, 0.f, 0.f, 0.f, 0.f, 0.f};
        int k = s0;
        for (; k + 1 < s1; k += 2) {
            ushort ra[8], rb[8];
            *(uint4*)ra = *(const uint4*)(O2 + (size_t)k * HD + f0);
            *(uint4*)rb = *(const uint4*)(O2 + (size_t)(k + 1) * HD + f0);
            #pragma unroll
            for (int j = 0; j < 8; j++) sum[j] += bf2f(ra[j]) + bf2f(rb[j]);
        }
        if (k < s1) {
            ushort ra[8];
            *(uint4*)ra = *(const uint4*)(O2 + (size_t)k * HD + f0);
            #pragma unroll
            for (int j = 0; j < 8; j++) sum[j] += bf2f(ra[j]);
        }
        ushort tmp[8];
        #pragma unroll
        for (int j = 0; j < 8; j++)
            tmp[j] = f2bf(0.125f * __logf(sum[j] + corr));
        *(uint4*)(Xs + row * PD + f0) = *(uint4*)tmp;
    }
    __syncthreads();

    const int wave = tid >> 6, lane = tid & 63;
    const int q = lane >> 4, ln = lane & 15;

    f32x4 acc[2][2];
    mfma_layer<128, 128, 2, PD>(wt1, b1, Xs, wave, lane, acc);
    #pragma unroll
    for (int mt = 0; mt < 2; mt++)
        #pragma unroll
        for (int nt = 0; nt < 2; nt++)
            #pragma unroll
            for (int r = 0; r < 4; r++)
                Hs[(mt * 16 + q * 4 + r) * PD + wave * 32 + nt * 16 + ln] =
                    f2bf(fmaxf(acc[mt][nt][r], 0.f));
    __syncthreads();

    f32x4 acc2[2][1];
    mfma_layer<128, 64, 1, PD>(wt2, b2, Hs, wave, lane, acc2);
    #pragma unroll
    for (int mt = 0; mt < 2; mt++)
        #pragma unroll
        for (int r = 0; r < 4; r++)
            out[(size_t)(r0 + mt * 16 + q * 4 + r) * HD + wave * 16 + ln] =
                acc2[mt][0][r];
}

// ================= update kernel: OLD (bf16-accum read, fallback) ============
__global__ __launch_bounds__(256) void update_mfma(
    const float* __restrict__ ns, const ushort* __restrict__ S16,
    const unsigned* __restrict__ Mword,
    const ushort* __restrict__ wt1, const float* __restrict__ b1,
    const ushort* __restrict__ wt2, const float* __restrict__ b2,
    float* __restrict__ out)
{
    constexpr int D = 128, PD = D + 8;
    __shared__ __align__(16) ushort Xs[32 * PD];
    __shared__ __align__(16) ushort Hs[32 * PD];

    const int tid = threadIdx.x;
    const int r0  = blockIdx.x * 32;
    const float corr = 1e-16f * __expf(8.f * dec_f32(*Mword));

    for (int lin = tid; lin < 32 * 16; lin += 256) {
        int row = lin >> 4, c8 = (lin & 15) * 8;
        ushort tmp[8];
        if (c8 < 64) {
            ushort raw[8];
            *(uint4*)raw = *(const uint4*)(S16 + (size_t)(r0 + row) * HD + c8);
            #pragma unroll
            for (int j = 0; j < 8; j++)
                tmp[j] = f2bf(0.125f * __logf(bf2f(raw[j]) + corr));
        } else {
            #pragma unroll
            for (int j = 0; j < 8; j++)
                tmp[j] = f2bf(ns[(size_t)(r0 + row) * HD + (c8 - 64) + j]);
        }
        *(uint4*)(Xs + row * PD + c8) = *(uint4*)tmp;
    }
    __syncthreads();

    const int wave = tid >> 6, lane = tid & 63;
    const int q = lane >> 4, ln = lane & 15;

    f32x4 acc[2][2];
    mfma_layer<128, 128, 2, PD>(wt1, b1, Xs, wave, lane, acc);
    #pragma unroll
    for (int mt = 0; mt < 2; mt++)
        #pragma unroll
        for (int nt = 0; nt < 2; nt++)
            #pragma unroll
            for (int r = 0; r < 4; r++)
                Hs[(mt * 16 + q * 4 + r) * PD + wave * 32 + nt * 16 + ln] =
                    f2bf(fmaxf(acc[mt][nt][r], 0.f));
    __syncthreads();

    f32x4 acc2[2][1];
    mfma_layer<128, 64, 1, PD>(wt2, b2, Hs, wave, lane, acc2);
    #pragma unroll
    for (int mt = 0; mt < 2; mt++)
        #pragma unroll
        for (int r = 0; r < 4; r++)
            out[(size_t)(r0 + mt * 16 + q * 4 + r) * HD + wave * 16 + ln] =
                acc2[mt][0][r];
}

// ================= host =====================================================
extern "C" void kernel_launch(void* const* d_in, const int* in_sizes, int n_in,
                              void* d_out, int out_size, void* d_ws, size_t ws_size,
                              hipStream_t stream)
{
    const float* ns   = (const float*)d_in[0];
    const int*   idx0 = (const int*)d_in[1];
    const int*   idx1 = (const int*)d_in[2];
    const int*   idx2 = (const int*)d_in[3];
    const float* W[8] = { (const float*)d_in[4],  (const float*)d_in[6],
                          (const float*)d_in[8],  (const float*)d_in[10],
                          (const float*)d_in[12], (const float*)d_in[14],
                          (const float*)d_in[16], (const float*)d_in[18] };
    const float* B[8] = { (const float*)d_in[5],  (const float*)d_in[7],
                          (const float*)d_in[9],  (const float*)d_in[11],
                          (const float*)d_in[13], (const float*)d_in[15],
                          (const float*)d_in[17], (const float*)d_in[19] };
    static const int DIN[8]  = {128,128,128,128,192,192,128,128};
    static const int DOUT[8] = {128,128,128,128,192,192,128, 64};

    const int n0f = in_sizes[1];          // 600000 flat ints
    const int n1f = in_sizes[2];          // 600000
    const int n2f = in_sizes[3];          // 600000
    const int TOT = n0f + n1f + n2f;      // 1,800,000
    const int T0 = n0f / 2, T1 = n1f / 2, T2 = n2f / 3;

    size_t wtot = 0;
    for (int m = 0; m < 8; m++) wtot += (size_t)DIN[m] * DOUT[m];   // 360,448

    // ---- new-path workspace layout ----
    size_t oO     = 0;
    size_t oNs    = oO  + (size_t)TOT * HD * 2;                     // O2: 230.4 MB
    size_t oWT    = oNs + (size_t)NS_ELEMS * 2;                     // ns16: 25.6 MB
    size_t oPerm  = oWT + ((wtot * 2 + 255) & ~(size_t)255);
    size_t oStart = oPerm + (((size_t)TOT * 4 + 255) & ~(size_t)255);
    size_t oOff   = oStart + (((size_t)(NNODES + 1) * 4 + 255) & ~(size_t)255);
    size_t oPart  = oOff + (size_t)NNODES * 4;
    size_t oCnt   = oPart + 4096;
    size_t oMw    = oCnt + (size_t)NNODES * 4;
    size_t NEED   = oMw + 64;

    if (ws_size >= NEED) {
        // ================= perm / streaming pipelined path =================
        ushort*   O2    = (ushort*)d_ws;
        ushort*   ns16  = (ushort*)((char*)d_ws + oNs);
        ushort*   WTb   = (ushort*)((char*)d_ws + oWT);
        int*      perm  = (int*)((char*)d_ws + oPerm);
        int*      start = (int*)((char*)d_ws + oStart);
        int*      offp  = (int*)((char*)d_ws + oOff);
        int*      part  = (int*)((char*)d_ws + oPart);
        int*      cnt   = (int*)((char*)d_ws + oCnt);
        unsigned* Mw    = (unsigned*)((char*)d_ws + oMw);

        PrepArgs pa;
        int total = NS_ELEMS;
        ushort* wt[8];
        {
            ushort* p = WTb;
            for (int m = 0; m < 8; m++) {
                pa.src[m] = W[m];
                pa.dst[m] = p;  wt[m] = p;
                pa.din[m] = DIN[m]; pa.dout[m] = DOUT[m];
                pa.nelem[m] = DIN[m] * DOUT[m];
                p += pa.nelem[m];
                total += pa.nelem[m];
            }
        }
        int histBase = total;
        total += TOT;                     // fused histogram range

        hipMemsetAsync((char*)d_ws + oCnt, 0, (size_t)NNODES * 4 + 64, stream);
        prep_kernel<<<4096, 256, 0, stream>>>(ns, ns16, pa, total,
                                              idx0, idx1, idx2, n0f, n0f + n1f,
                                              histBase, cnt);

        const int NB   = (NNODES + 255) / 256;
        const int gTOT = (TOT + 255) / 256;
        scan1_kernel<<<NB, 256, 0, stream>>>(cnt, start, part, NNODES);
        scan2_kernel<<<1, 1024, 0, stream>>>(part, NB);
        scan3_kernel<<<NB, 256, 0, stream>>>(start, offp, part, NNODES, TOT);
        fill_perm<<<gTOT, 256, 0, stream>>>(idx0, idx1, idx2, n0f, n0f + n1f, TOT, offp, perm);

        // persistent pipelined rel kernels (round-3 grids: measured best)
        int nt0 = T0 / 32, nt1 = T1 / 32, nt2 = T2 / 32;
        int g2a = nt0 < 1536 ? nt0 : 1536;
        int g2b = nt1 < 1536 ? nt1 : 1536;
        int g3  = nt2 < 1024 ? nt2 : 1024;

        rel_mfma_pp<2><<<g2a, 256, 0, stream>>>(
            ns16, idx0, perm, wt[0], B[0], wt[1], B[1], O2, Mw, nt0);
        rel_mfma_pp<2><<<g2b, 256, 0, stream>>>(
            ns16, idx1, perm + n0f, wt[2], B[2], wt[3], B[3], O2, Mw, nt1);
        rel_mfma_pp<3><<<g3, 256, 0, stream>>>(
            ns16, idx2, perm + n0f + n1f, wt[4], B[4], wt[5], B[5], O2, Mw, nt2);

        update_lin<<<NNODES / 32, 256, 0, stream>>>(
            ns, O2, start, Mw, wt[6], B[6], wt[7], B[7], (float*)d_out);
    } else {
        // ================= fallback: atomic path =================
        ushort*   S16  = (ushort*)d_ws;
        size_t    offM = (size_t)NNODES * HD * sizeof(ushort);
        unsigned* Mw   = (unsigned*)((char*)d_ws + offM);
        ushort*   ns16 = (ushort*)((char*)d_ws + offM + 64);
        ushort*   WTb  = ns16 + (size_t)NS_ELEMS;

        PrepArgs pa;
        int total = NS_ELEMS;
        ushort* wt[8];
        {
            ushort* p = WTb;
            for (int m = 0; m < 8; m++) {
                pa.src[m] = W[m];
                pa.dst[m] = p;  wt[m] = p;
                pa.din[m] = DIN[m]; pa.dout[m] = DOUT[m];
                pa.nelem[m] = DIN[m] * DOUT[m];
                p += pa.nelem[m];
                total += pa.nelem[m];
            }
        }

        hipMemsetAsync(d_ws, 0, offM + 64, stream);
        prep_kernel<<<4096, 256, 0, stream>>>(ns, ns16, pa, total,
                                              idx0, idx1, idx2, n0f, n0f + n1f,
                                              total, (int*)Mw /*unused*/);

        rel_mfma<2><<<T0 / 32, 256, 0, stream>>>(ns16, idx0, wt[0], B[0], wt[1], B[1], S16, Mw);
        rel_mfma<2><<<T1 / 32, 256, 0, stream>>>(ns16, idx1, wt[2], B[2], wt[3], B[3], S16, Mw);
        rel_mfma<3><<<T2 / 32, 256, 0, stream>>>(ns16, idx2, wt[4], B[4], wt[5], B[5], S16, Mw);
        update_mfma<<<NNODES / 32, 256, 0, stream>>>(ns, S16, Mw, wt[6], B[6], wt[7], B[7],
                                                     (float*)d_out);
    }
}

// Round 13
// 515.114 us; speedup vs baseline: 2.0289x; 1.0962x over previous
//
#include <hip/hip_runtime.h>
#include <cstdint>

#define HD 64
#define NNODES 200000
#define NS_ELEMS (NNODES * HD)          // 12,800,000

typedef short bf8 __attribute__((ext_vector_type(8)));
typedef short s2v __attribute__((ext_vector_type(2)));
typedef float f32x4 __attribute__((ext_vector_type(4)));

// ---- order-preserving float <-> uint for atomicMax ----
__device__ __forceinline__ unsigned enc_f32(float f) {
    unsigned u = __float_as_uint(f);
    return (u & 0x80000000u) ? ~u : (u | 0x80000000u);
}
__device__ __forceinline__ float dec_f32(unsigned v) {
    return (v & 0x80000000u) ? __uint_as_float(v & 0x7fffffffu)
                             : __uint_as_float(~v);
}

// RNE float -> bf16 bits, and back
__device__ __forceinline__ ushort f2bf(float f) {
    unsigned u = __float_as_uint(f);
    return (ushort)((u + 0x7fffu + ((u >> 16) & 1u)) >> 16);
}
__device__ __forceinline__ float bf2f(ushort b) {
    return __uint_as_float(((unsigned)b) << 16);
}

// ---- packed 2x bf16 atomic add (fallback path only) ----
__device__ __forceinline__ void atom_pk_add_bf16(ushort* p, ushort lo, ushort hi) {
    s2v v; v[0] = (short)lo; v[1] = (short)hi;
#if __has_builtin(__builtin_amdgcn_flat_atomic_fadd_v2bf16)
    (void)__builtin_amdgcn_flat_atomic_fadd_v2bf16((s2v*)p, v);
#elif __has_builtin(__builtin_amdgcn_global_atomic_fadd_v2bf16)
    (void)__builtin_amdgcn_global_atomic_fadd_v2bf16(
        (__attribute__((address_space(1))) s2v*)p, v);
#else
    unsigned* a = (unsigned*)p;
    unsigned old = *a, assumed;
    do {
        assumed = old;
        float f0 = bf2f((ushort)(assumed & 0xffffu)) + bf2f(lo);
        float f1 = bf2f((ushort)(assumed >> 16))     + bf2f(hi);
        unsigned nv = (unsigned)f2bf(f0) | ((unsigned)f2bf(f1) << 16);
        old = atomicCAS(a, assumed, nv);
    } while (old != assumed);
#endif
}

// ====== prep: ns fp32->bf16; weights fp32 -> bf16 frag-linear; + hist =======
struct PrepArgs {
    const float* src[8];
    ushort*      dst[8];
    int din[8], dout[8], nelem[8];
};

__global__ __launch_bounds__(256) void prep_kernel(
    const float* __restrict__ ns, ushort* __restrict__ ns16, PrepArgs pa, int total,
    const int* __restrict__ i0, const int* __restrict__ i1, const int* __restrict__ i2,
    int b1e, int b2e, int histBase, int* __restrict__ cnt)
{
    int stride = gridDim.x * 256;
    for (int i = blockIdx.x * 256 + threadIdx.x; i < total; i += stride) {
        if (i >= histBase) {
            // fused histogram over all flat idx entries
            int s = i - histBase;
            int node = (s < b1e) ? i0[s] : (s < b2e ? i1[s - b1e] : i2[s - b2e]);
            atomicAdd(&cnt[node], 1);
            continue;
        }
        if (i < NS_ELEMS) { ns16[i] = f2bf(ns[i]); continue; }
        int e = i - NS_ELEMS;
        #pragma unroll
        for (int m = 0; m < 8; m++) {
            if (e < pa.nelem[m]) {
                int din = pa.din[m], dout = pa.dout[m];
                int n = e / din, k = e - n * din;
                pa.dst[m][(k >> 5) * dout * 32 + n * 32 + (k & 31)] = f2bf(pa.src[m][e]);
                e = 0x7fffffff;
            } else {
                e -= pa.nelem[m];
            }
        }
    }
}

// ================= CSR build: scan =========================================
__global__ __launch_bounds__(256) void scan1_kernel(
    const int* __restrict__ cnt, int* __restrict__ startv,
    int* __restrict__ partials, int n)
{
    __shared__ int wsum[4];
    int i = blockIdx.x * 256 + threadIdx.x;
    int v = (i < n) ? cnt[i] : 0;
    int lane = threadIdx.x & 63, wid = threadIdx.x >> 6;
    int x = v;
    #pragma unroll
    for (int off = 1; off < 64; off <<= 1) {
        int y = __shfl_up(x, off);
        if (lane >= off) x += y;
    }
    if (lane == 63) wsum[wid] = x;
    __syncthreads();
    int woff = 0;
    for (int w = 0; w < wid; w++) woff += wsum[w];
    int incl = x + woff;
    if (i < n) startv[i] = incl - v;              // block-local exclusive
    if (threadIdx.x == 255) partials[blockIdx.x] = incl;
}

__global__ __launch_bounds__(1024) void scan2_kernel(int* __restrict__ partials, int nb)
{
    __shared__ int sh[1024];
    int t = threadIdx.x;
    int orig = (t < nb) ? partials[t] : 0;
    sh[t] = orig;
    __syncthreads();
    for (int off = 1; off < 1024; off <<= 1) {
        int v = (t >= off) ? sh[t - off] : 0;
        __syncthreads();
        sh[t] += v;
        __syncthreads();
    }
    if (t < nb) partials[t] = sh[t] - orig;       // exclusive
}

__global__ __launch_bounds__(256) void scan3_kernel(
    int* __restrict__ startv, int* __restrict__ offv,
    const int* __restrict__ partials, int n, int total)
{
    int i = blockIdx.x * 256 + threadIdx.x;
    if (i < n) {
        int s = startv[i] + partials[blockIdx.x];
        startv[i] = s;
        offv[i] = s;
    }
    if (i == 0) startv[n] = total;
}

// ================= one MFMA dense layer over a 32-row LDS tile ===============
template<int DIN, int DOUT, int NT, int PDIN>
__device__ __forceinline__ void mfma_layer(
    const ushort* __restrict__ WT, const float* __restrict__ bias,
    const ushort* __restrict__ Xs, int wave, int lane, f32x4 acc[2][NT])
{
    constexpr int KS = DIN / 32;
    const int q = lane >> 4, ln = lane & 15;
    const int n0 = wave * NT * 16;
    bf8 bf[NT][KS];
    #pragma unroll
    for (int nt = 0; nt < NT; nt++) {
        float bv = bias[n0 + nt * 16 + ln];
        acc[0][nt] = f32x4{bv, bv, bv, bv};
        acc[1][nt] = f32x4{bv, bv, bv, bv};
        #pragma unroll
        for (int ks = 0; ks < KS; ks++)
            bf[nt][ks] = *(const bf8*)(WT + (size_t)ks * DOUT * 32
                                          + (n0 + nt * 16 + ln) * 32 + q * 8);
    }
    #pragma unroll
    for (int mt = 0; mt < 2; mt++) {
        bf8 af[KS];
        #pragma unroll
        for (int ks = 0; ks < KS; ks++)
            af[ks] = *(const bf8*)(Xs + (mt * 16 + ln) * PDIN + ks * 32 + q * 8);
        #pragma unroll
        for (int ks = 0; ks < KS; ks++)
            #pragma unroll
            for (int nt = 0; nt < NT; nt++)
                acc[mt][nt] = __builtin_amdgcn_mfma_f32_16x16x32_bf16(
                    af[ks], bf[nt][ks], acc[mt][nt], 0, 0, 0);
    }
}

// ====== relation kernel: round-3 structure + INLINE row-claim (no fill_perm)
// Row in the destination segment is claimed via atomicAdd on the per-node
// cursor (offp, L2-hot 800KB). Any claim order is a bijection into the
// node's segment, so correctness matches the old precomputed perm.
template<int A>
__global__ __launch_bounds__(256) void rel_mfma_pp(
    const ushort* __restrict__ ns16, const int* __restrict__ idx,
    int* __restrict__ offp,
    const ushort* __restrict__ wt1, const float* __restrict__ b1,
    const ushort* __restrict__ wt2, const float* __restrict__ b2,
    ushort* __restrict__ O2, unsigned* __restrict__ Mword, int ntiles)
{
    constexpr int D  = A * HD;
    constexpr int PD = D + 8;
    constexpr int NT = D / 64;
    __shared__ __align__(16) ushort Xs[2][32 * PD];
    __shared__ __align__(16) ushort Hs[32 * PD];
    __shared__ int Pr[2][32 * A];
    __shared__ float wred[4];

    const int tid  = threadIdx.x;
    const int wave = tid >> 6, lane = tid & 63;
    const int q = lane >> 4, ln = lane & 15, n0 = wave * NT * 16;

    uint4 greg[A];
    int   pv = 0;
    float mblk = -3.0e38f;

    int ti = blockIdx.x;
    if (ti < ntiles) {
        int t0 = ti * 32;
        #pragma unroll
        for (int k = 0; k < A; k++) {
            int j = tid + k * 256;
            int slot = j >> 3, part = j & 7;
            int node = idx[t0 * A + slot];
            greg[k] = *(const uint4*)(ns16 + (size_t)node * HD + part * 8);
        }
        if (tid < 32 * A) {
            int nd = idx[t0 * A + tid];
            pv = atomicAdd(&offp[nd], 1);          // claim my output row
        }
        #pragma unroll
        for (int k = 0; k < A; k++) {
            int j = tid + k * 256;
            int slot = j >> 3, part = j & 7;
            int row = slot / A, sub = slot - row * A;
            *(uint4*)(&Xs[0][row * PD + sub * 64 + part * 8]) = greg[k];
        }
        if (tid < 32 * A) Pr[0][tid] = pv;
        __syncthreads();

        int cur = 0;
        for (;;) {
            int tn = ti + gridDim.x;
            bool has_next = tn < ntiles;
            if (has_next) {
                int t0n = tn * 32;
                #pragma unroll
                for (int k = 0; k < A; k++) {
                    int j = tid + k * 256;
                    int slot = j >> 3, part = j & 7;
                    int node = idx[t0n * A + slot];
                    greg[k] = *(const uint4*)(ns16 + (size_t)node * HD + part * 8);
                }
                if (tid < 32 * A) {
                    int nd = idx[t0n * A + tid];
                    pv = atomicAdd(&offp[nd], 1);  // claim next tile's row
                }
            }

            f32x4 acc[2][NT];
            mfma_layer<D, D, NT, PD>(wt1, b1, Xs[cur], wave, lane, acc);
            #pragma unroll
            for (int mt = 0; mt < 2; mt++)
                #pragma unroll
                for (int nt = 0; nt < NT; nt++)
                    #pragma unroll
                    for (int r = 0; r < 4; r++)
                        Hs[(mt * 16 + q * 4 + r) * PD + n0 + nt * 16 + ln] =
                            f2bf(fmaxf(acc[mt][nt][r], 0.f));
            __syncthreads();                       // (1) Hs ready for layer2
            mfma_layer<D, D, NT, PD>(wt2, b2, Hs, wave, lane, acc);
            __syncthreads();                       // (2) Hs reads done

            #pragma unroll
            for (int mt = 0; mt < 2; mt++)
                #pragma unroll
                for (int nt = 0; nt < NT; nt++) {
                    int colg = n0 + nt * 16 + ln;
                    #pragma unroll
                    for (int r = 0; r < 4; r++) {
                        float o = acc[mt][nt][r];
                        mblk = fmaxf(mblk, o);
                        Hs[(mt * 16 + q * 4 + r) * PD + colg] = f2bf(__expf(8.f * o));
                    }
                }
            __syncthreads();                       // (3) exp rows ready

            #pragma unroll
            for (int k = 0; k < A; k++) {
                int j = tid + k * 256;
                int slot = j >> 3, part = j & 7;
                int row = slot / A, sub = slot - row * A;
                *(uint4*)(O2 + (size_t)Pr[cur][slot] * HD + part * 8) =
                    *(const uint4*)(&Hs[row * PD + sub * 64 + part * 8]);
            }

            if (!has_next) break;

            __syncthreads();                       // (4) Hs scatter-reads done
            int nxt = cur ^ 1;
            #pragma unroll
            for (int k = 0; k < A; k++) {
                int j = tid + k * 256;
                int slot = j >> 3, part = j & 7;
                int row = slot / A, sub = slot - row * A;
                *(uint4*)(&Xs[nxt][row * PD + sub * 64 + part * 8]) = greg[k];
            }
            if (tid < 32 * A) Pr[nxt][tid] = pv;
            __syncthreads();                       // (5) Xs[nxt]/Pr[nxt] ready
            cur = nxt;
            ti = tn;
        }
    }

    #pragma unroll
    for (int off = 32; off; off >>= 1) mblk = fmaxf(mblk, __shfl_xor(mblk, off));
    if (lane == 0) wred[wave] = mblk;
    __syncthreads();
    if (tid == 0)
        atomicMax(Mword, enc_f32(fmaxf(fmaxf(wred[0], wred[1]),
                                       fmaxf(wred[2], wred[3]))));
}

// ================= relation kernel: OLD (atomic scatter, fallback) ===========
template<int A>
__global__ __launch_bounds__(256) void rel_mfma(
    const ushort* __restrict__ ns16, const int* __restrict__ idx,
    const ushort* __restrict__ wt1, const float* __restrict__ b1,
    const ushort* __restrict__ wt2, const float* __restrict__ b2,
    ushort* __restrict__ S16, unsigned* __restrict__ Mword)
{
    constexpr int D  = A * HD;
    constexpr int PD = D + 8;
    constexpr int NT = D / 64;
    __shared__ __align__(16) ushort Xs[32 * PD];
    __shared__ __align__(16) ushort Hs[32 * PD];
    __shared__ int Is[32 * A];
    __shared__ float wred[4];

    const int tid = threadIdx.x;
    const int t0  = blockIdx.x * 32;

    if (tid < 32 * A) Is[tid] = idx[t0 * A + tid];
    for (int lin = tid; lin < 32 * A * 8; lin += 256) {
        int slot = lin >> 3, part = lin & 7;
        int node = idx[t0 * A + slot];
        int row = slot / A, sub = slot - row * A;
        *(uint4*)(Xs + row * PD + sub * 64 + part * 8) =
            *(const uint4*)(ns16 + (size_t)node * HD + part * 8);
    }
    __syncthreads();

    const int wave = tid >> 6, lane = tid & 63;
    const int q = lane >> 4, ln = lane & 15, n0 = wave * NT * 16;

    f32x4 acc[2][NT];
    mfma_layer<D, D, NT, PD>(wt1, b1, Xs, wave, lane, acc);
    #pragma unroll
    for (int mt = 0; mt < 2; mt++)
        #pragma unroll
        for (int nt = 0; nt < NT; nt++)
            #pragma unroll
            for (int r = 0; r < 4; r++)
                Hs[(mt * 16 + q * 4 + r) * PD + n0 + nt * 16 + ln] =
                    f2bf(fmaxf(acc[mt][nt][r], 0.f));
    __syncthreads();
    mfma_layer<D, D, NT, PD>(wt2, b2, Hs, wave, lane, acc);

    float m = -3.0e38f;
    const bool even = (ln & 1) == 0;
    #pragma unroll
    for (int mt = 0; mt < 2; mt++)
        #pragma unroll
        for (int nt = 0; nt < NT; nt++) {
            int colg = n0 + nt * 16 + ln;
            int sub  = colg >> 6;
            int featp = (colg & 63) & ~1;
            float e[4], p[4];
            #pragma unroll
            for (int r = 0; r < 4; r++) {
                float o = acc[mt][nt][r];
                m = fmaxf(m, o);
                e[r] = __expf(8.f * o);
            }
            #pragma unroll
            for (int r = 0; r < 4; r++) p[r] = __shfl_xor(e[r], 1);
            #pragma unroll
            for (int j = 0; j < 2; j++) {
                int r   = even ? j : (2 + j);
                int row = mt * 16 + q * 4 + r;
                int node = Is[row * A + sub];
                ushort lo = even ? f2bf(e[r]) : f2bf(p[r]);
                ushort hi = even ? f2bf(p[r]) : f2bf(e[r]);
                atom_pk_add_bf16(S16 + (size_t)node * HD + featp, lo, hi);
            }
        }
    #pragma unroll
    for (int off = 32; off; off >>= 1) m = fmaxf(m, __shfl_xor(m, off));
    if (lane == 0) wred[wave] = m;
    __syncthreads();
    if (tid == 0)
        atomicMax(Mword, enc_f32(fmaxf(fmaxf(wred[0], wred[1]),
                                       fmaxf(wred[2], wred[3]))));
}

// ===== update kernel: contiguous segment reduce (streaming) + MFMA ==========
__global__ __launch_bounds__(256) void update_lin(
    const float* __restrict__ ns, const ushort* __restrict__ O2,
    const int* __restrict__ startv,
    const unsigned* __restrict__ Mword,
    const ushort* __restrict__ wt1, const float* __restrict__ b1,
    const ushort* __restrict__ wt2, const float* __restrict__ b2,
    float* __restrict__ out)
{
    constexpr int D = 128, PD = D + 8;
    __shared__ __align__(16) ushort Xs[32 * PD];
    __shared__ __align__(16) ushort Hs[32 * PD];

    const int tid = threadIdx.x;
    const int r0  = blockIdx.x * 32;
    const float corr = 1e-16f * __expf(8.f * dec_f32(*Mword));

    // ns half: rows 0..31, cols 64..127
    for (int lin = tid; lin < 32 * 8; lin += 256) {
        int row = lin >> 3, p8 = (lin & 7) * 8;
        const float* src = ns + (size_t)(r0 + row) * HD + p8;
        float4 a = *(const float4*)src;
        float4 b = *(const float4*)(src + 4);
        ushort tmp[8] = { f2bf(a.x), f2bf(a.y), f2bf(a.z), f2bf(a.w),
                          f2bf(b.x), f2bf(b.y), f2bf(b.z), f2bf(b.w) };
        *(uint4*)(Xs + row * PD + 64 + p8) = *(uint4*)tmp;
    }

    // segmented reduce over CONTIGUOUS rows
    {
        const int row = tid >> 3, f0 = (tid & 7) * 8;
        const int s0 = startv[r0 + row];
        const int s1 = startv[r0 + row + 1];
        float sum[8] = {0.f, 0.f, 0.f, 0.f, 0.f, 0.f, 0.f, 0.f};
        int k = s0;
        for (; k + 1 < s1; k += 2) {
            ushort ra[8], rb[8];
            *(uint4*)ra = *(const uint4*)(O2 + (size_t)k * HD + f0);
            *(uint4*)rb = *(const uint4*)(O2 + (size_t)(k + 1) * HD + f0);
            #pragma unroll
            for (int j = 0; j < 8; j++) sum[j] += bf2f(ra[j]) + bf2f(rb[j]);
        }
        if (k < s1) {
            ushort ra[8];
            *(uint4*)ra = *(const uint4*)(O2 + (size_t)k * HD + f0);
            #pragma unroll
            for (int j = 0; j < 8; j++) sum[j] += bf2f(ra[j]);
        }
        ushort tmp[8];
        #pragma unroll
        for (int j = 0; j < 8; j++)
            tmp[j] = f2bf(0.125f * __logf(sum[j] + corr));
        *(uint4*)(Xs + row * PD + f0) = *(uint4*)tmp;
    }
    __syncthreads();

    const int wave = tid >> 6, lane = tid & 63;
    const int q = lane >> 4, ln = lane & 15;

    f32x4 acc[2][2];
    mfma_layer<128, 128, 2, PD>(wt1, b1, Xs, wave, lane, acc);
    #pragma unroll
    for (int mt = 0; mt < 2; mt++)
        #pragma unroll
        for (int nt = 0; nt < 2; nt++)
            #pragma unroll
            for (int r = 0; r < 4; r++)
                Hs[(mt * 16 + q * 4 + r) * PD + wave * 32 + nt * 16 + ln] =
                    f2bf(fmaxf(acc[mt][nt][r], 0.f));
    __syncthreads();

    f32x4 acc2[2][1];
    mfma_layer<128, 64, 1, PD>(wt2, b2, Hs, wave, lane, acc2);
    #pragma unroll
    for (int mt = 0; mt < 2; mt++)
        #pragma unroll
        for (int r = 0; r < 4; r++)
            out[(size_t)(r0 + mt * 16 + q * 4 + r) * HD + wave * 16 + ln] =
                acc2[mt][0][r];
}

// ================= update kernel: OLD (bf16-accum read, fallback) ============
__global__ __launch_bounds__(256) void update_mfma(
    const float* __restrict__ ns, const ushort* __restrict__ S16,
    const unsigned* __restrict__ Mword,
    const ushort* __restrict__ wt1, const float* __restrict__ b1,
    const ushort* __restrict__ wt2, const float* __restrict__ b2,
    float* __restrict__ out)
{
    constexpr int D = 128, PD = D + 8;
    __shared__ __align__(16) ushort Xs[32 * PD];
    __shared__ __align__(16) ushort Hs[32 * PD];

    const int tid = threadIdx.x;
    const int r0  = blockIdx.x * 32;
    const float corr = 1e-16f * __expf(8.f * dec_f32(*Mword));

    for (int lin = tid; lin < 32 * 16; lin += 256) {
        int row = lin >> 4, c8 = (lin & 15) * 8;
        ushort tmp[8];
        if (c8 < 64) {
            ushort raw[8];
            *(uint4*)raw = *(const uint4*)(S16 + (size_t)(r0 + row) * HD + c8);
            #pragma unroll
            for (int j = 0; j < 8; j++)
                tmp[j] = f2bf(0.125f * __logf(bf2f(raw[j]) + corr));
        } else {
            #pragma unroll
            for (int j = 0; j < 8; j++)
                tmp[j] = f2bf(ns[(size_t)(r0 + row) * HD + (c8 - 64) + j]);
        }
        *(uint4*)(Xs + row * PD + c8) = *(uint4*)tmp;
    }
    __syncthreads();

    const int wave = tid >> 6, lane = tid & 63;
    const int q = lane >> 4, ln = lane & 15;

    f32x4 acc[2][2];
    mfma_layer<128, 128, 2, PD>(wt1, b1, Xs, wave, lane, acc);
    #pragma unroll
    for (int mt = 0; mt < 2; mt++)
        #pragma unroll
        for (int nt = 0; nt < 2; nt++)
            #pragma unroll
            for (int r = 0; r < 4; r++)
                Hs[(mt * 16 + q * 4 + r) * PD + wave * 32 + nt * 16 + ln] =
                    f2bf(fmaxf(acc[mt][nt][r], 0.f));
    __syncthreads();

    f32x4 acc2[2][1];
    mfma_layer<128, 64, 1, PD>(wt2, b2, Hs, wave, lane, acc2);
    #pragma unroll
    for (int mt = 0; mt < 2; mt++)
        #pragma unroll
        for (int r = 0; r < 4; r++)
            out[(size_t)(r0 + mt * 16 + q * 4 + r) * HD + wave * 16 + ln] =
                acc2[mt][0][r];
}

// ================= host =====================================================
extern "C" void kernel_launch(void* const* d_in, const int* in_sizes, int n_in,
                              void* d_out, int out_size, void* d_ws, size_t ws_size,
                              hipStream_t stream)
{
    const float* ns   = (const float*)d_in[0];
    const int*   idx0 = (const int*)d_in[1];
    const int*   idx1 = (const int*)d_in[2];
    const int*   idx2 = (const int*)d_in[3];
    const float* W[8] = { (const float*)d_in[4],  (const float*)d_in[6],
                          (const float*)d_in[8],  (const float*)d_in[10],
                          (const float*)d_in[12], (const float*)d_in[14],
                          (const float*)d_in[16], (const float*)d_in[18] };
    const float* B[8] = { (const float*)d_in[5],  (const float*)d_in[7],
                          (const float*)d_in[9],  (const float*)d_in[11],
                          (const float*)d_in[13], (const float*)d_in[15],
                          (const float*)d_in[17], (const float*)d_in[19] };
    static const int DIN[8]  = {128,128,128,128,192,192,128,128};
    static const int DOUT[8] = {128,128,128,128,192,192,128, 64};

    const int n0f = in_sizes[1];          // 600000 flat ints
    const int n1f = in_sizes[2];          // 600000
    const int n2f = in_sizes[3];          // 600000
    const int TOT = n0f + n1f + n2f;      // 1,800,000
    const int T0 = n0f / 2, T1 = n1f / 2, T2 = n2f / 3;

    size_t wtot = 0;
    for (int m = 0; m < 8; m++) wtot += (size_t)DIN[m] * DOUT[m];   // 360,448

    // ---- new-path workspace layout (perm slot retained but unused) ----
    size_t oO     = 0;
    size_t oNs    = oO  + (size_t)TOT * HD * 2;                     // O2: 230.4 MB
    size_t oWT    = oNs + (size_t)NS_ELEMS * 2;                     // ns16: 25.6 MB
    size_t oPerm  = oWT + ((wtot * 2 + 255) & ~(size_t)255);
    size_t oStart = oPerm + (((size_t)TOT * 4 + 255) & ~(size_t)255);
    size_t oOff   = oStart + (((size_t)(NNODES + 1) * 4 + 255) & ~(size_t)255);
    size_t oPart  = oOff + (size_t)NNODES * 4;
    size_t oCnt   = oPart + 4096;
    size_t oMw    = oCnt + (size_t)NNODES * 4;
    size_t NEED   = oMw + 64;

    if (ws_size >= NEED) {
        // ================= perm / streaming pipelined path =================
        ushort*   O2    = (ushort*)d_ws;
        ushort*   ns16  = (ushort*)((char*)d_ws + oNs);
        ushort*   WTb   = (ushort*)((char*)d_ws + oWT);
        int*      start = (int*)((char*)d_ws + oStart);
        int*      offp  = (int*)((char*)d_ws + oOff);
        int*      part  = (int*)((char*)d_ws + oPart);
        int*      cnt   = (int*)((char*)d_ws + oCnt);
        unsigned* Mw    = (unsigned*)((char*)d_ws + oMw);

        PrepArgs pa;
        int total = NS_ELEMS;
        ushort* wt[8];
        {
            ushort* p = WTb;
            for (int m = 0; m < 8; m++) {
                pa.src[m] = W[m];
                pa.dst[m] = p;  wt[m] = p;
                pa.din[m] = DIN[m]; pa.dout[m] = DOUT[m];
                pa.nelem[m] = DIN[m] * DOUT[m];
                p += pa.nelem[m];
                total += pa.nelem[m];
            }
        }
        int histBase = total;
        total += TOT;                     // fused histogram range

        hipMemsetAsync((char*)d_ws + oCnt, 0, (size_t)NNODES * 4 + 64, stream);
        prep_kernel<<<4096, 256, 0, stream>>>(ns, ns16, pa, total,
                                              idx0, idx1, idx2, n0f, n0f + n1f,
                                              histBase, cnt);

        const int NB = (NNODES + 255) / 256;
        scan1_kernel<<<NB, 256, 0, stream>>>(cnt, start, part, NNODES);
        scan2_kernel<<<1, 1024, 0, stream>>>(part, NB);
        scan3_kernel<<<NB, 256, 0, stream>>>(start, offp, part, NNODES, TOT);
        // (fill_perm eliminated: rel kernels claim rows inline via offp)

        // persistent pipelined rel kernels (round-3 grids: measured best)
        int nt0 = T0 / 32, nt1 = T1 / 32, nt2 = T2 / 32;
        int g2a = nt0 < 1536 ? nt0 : 1536;
        int g2b = nt1 < 1536 ? nt1 : 1536;
        int g3  = nt2 < 1024 ? nt2 : 1024;

        rel_mfma_pp<2><<<g2a, 256, 0, stream>>>(
            ns16, idx0, offp, wt[0], B[0], wt[1], B[1], O2, Mw, nt0);
        rel_mfma_pp<2><<<g2b, 256, 0, stream>>>(
            ns16, idx1, offp, wt[2], B[2], wt[3], B[3], O2, Mw, nt1);
        rel_mfma_pp<3><<<g3, 256, 0, stream>>>(
            ns16, idx2, offp, wt[4], B[4], wt[5], B[5], O2, Mw, nt2);

        update_lin<<<NNODES / 32, 256, 0, stream>>>(
            ns, O2, start, Mw, wt[6], B[6], wt[7], B[7], (float*)d_out);
    } else {
        // ================= fallback: atomic path =================
        ushort*   S16  = (ushort*)d_ws;
        size_t    offM = (size_t)NNODES * HD * sizeof(ushort);
        unsigned* Mw   = (unsigned*)((char*)d_ws + offM);
        ushort*   ns16 = (ushort*)((char*)d_ws + offM + 64);
        ushort*   WTb  = ns16 + (size_t)NS_ELEMS;

        PrepArgs pa;
        int total = NS_ELEMS;
        ushort* wt[8];
        {
            ushort* p = WTb;
            for (int m = 0; m < 8; m++) {
                pa.src[m] = W[m];
                pa.dst[m] = p;  wt[m] = p;
                pa.din[m] = DIN[m]; pa.dout[m] = DOUT[m];
                pa.nelem[m] = DIN[m] * DOUT[m];
                p += pa.nelem[m];
                total += pa.nelem[m];
            }
        }

        hipMemsetAsync(d_ws, 0, offM + 64, stream);
        prep_kernel<<<4096, 256, 0, stream>>>(ns, ns16, pa, total,
                                              idx0, idx1, idx2, n0f, n0f + n1f,
                                              total, (int*)Mw /*unused*/);

        rel_mfma<2><<<T0 / 32, 256, 0, stream>>>(ns16, idx0, wt[0], B[0], wt[1], B[1], S16, Mw);
        rel_mfma<2><<<T1 / 32, 256, 0, stream>>>(ns16, idx1, wt[2], B[2], wt[3], B[3], S16, Mw);
        rel_mfma<3><<<T2 / 32, 256, 0, stream>>>(ns16, idx2, wt[4], B[4], wt[5], B[5], S16, Mw);
        update_mfma<<<NNODES / 32, 256, 0, stream>>>(ns, S16, Mw, wt[6], B[6], wt[7], B[7],
                                                     (float*)d_out);
    }
}